// Round 2
// baseline (481.289 us; speedup 1.0000x reference)
//
#include <hip/hip_runtime.h>

#define DEV __device__ __forceinline__

constexpr int B_ = 2, C_ = 64, H_ = 96, W_ = 96, L_ = 9216;
constexpr int HD_ = 32, DI_ = 64, N_ = 16, K_ = 4, BB_ = 4;
constexpr int OC_ = 128;
constexpr int CH_ = 96, CL_ = 96;           // scan chunking: 96 chunks of 96 steps
constexpr float EPSF = 1e-5f;
constexpr int DOWN_SZ = B_ * OC_ * 48 * 48; // 589824

// scan-order l -> spatial index for direction k
DEV int map_dir(int k, int l) {
  if (k & 2) l = L_ - 1 - l;
  if (k & 1) return (l % H_) * W_ + (l / H_);
  return l;
}

// ---------------- A: depthwise 3x3 (x -> xd, f32) ----------------
__global__ void k_dw33(const float* __restrict__ x, const float* __restrict__ w,
                       const float* __restrict__ bias, float* __restrict__ out) {
  int t = blockIdx.x * 256 + threadIdx.x;
  if (t >= B_ * C_ * L_) return;
  int wi = t % W_, hi = (t / W_) % H_, c = (t / L_) % C_;
  float acc = bias[c];
#pragma unroll
  for (int dy = -1; dy <= 1; dy++) {
    int hh = hi + dy; if (hh < 0 || hh >= H_) continue;
#pragma unroll
    for (int dx = -1; dx <= 1; dx++) {
      int ww = wi + dx; if (ww < 0 || ww >= W_) continue;
      acc = fmaf(x[t + dy * W_ + dx], w[c * 9 + (dy + 1) * 3 + (dx + 1)], acc);
    }
  }
  out[t] = acc;
}

// ---------------- B: LayerNorm(32ch) + in_proj (32->128) -> xz (BB,L,128) ----------------
__global__ void k_ln_inproj(const float* __restrict__ xd, const float* __restrict__ lnw,
                            const float* __restrict__ lnb, const float* __restrict__ inw,
                            float* __restrict__ xz) {
  int idx = blockIdx.x, bb = blockIdx.y, lane = threadIdx.x;
  int b = bb & 1, co = (bb >> 1) * HD_;
  float v = 0.f;
  if (lane < HD_) v = xd[(size_t)(b * C_ + co + lane) * L_ + idx];
  float s = v, sq = v * v;
#pragma unroll
  for (int m = 1; m < 64; m <<= 1) { s += __shfl_xor(s, m, 64); sq += __shfl_xor(sq, m, 64); }
  float mean = s * (1.f / HD_);
  float var = sq * (1.f / HD_) - mean * mean;
  float rstd = rsqrtf(var + EPSF);
  __shared__ float xn[HD_];
  if (lane < HD_) xn[lane] = (v - mean) * rstd * lnw[lane] + lnb[lane];
  __syncthreads();
  float a0 = 0.f, a1 = 0.f;
#pragma unroll
  for (int c = 0; c < HD_; c++) {
    float xv = xn[c];
    a0 = fmaf(xv, inw[c * 128 + lane], a0);
    a1 = fmaf(xv, inw[c * 128 + 64 + lane], a1);
  }
  float* o = xz + (size_t)(bb * L_ + idx) * 128;
  o[lane] = a0; o[64 + lane] = a1;
}

// ---------------- C: depthwise 3x3 + SiLU -> xc (BB,L,64) ----------------
__global__ void k_dwsilu(const float* __restrict__ xz, const float* __restrict__ cw,
                         const float* __restrict__ cb, float* __restrict__ xc) {
  int idx = blockIdx.x, bb = blockIdx.y, d = threadIdx.x;
  int wi = idx % W_, hi = idx / W_;
  float acc = cb[d];
#pragma unroll
  for (int dy = -1; dy <= 1; dy++) {
    int hh = hi + dy; if (hh < 0 || hh >= H_) continue;
#pragma unroll
    for (int dx = -1; dx <= 1; dx++) {
      int ww = wi + dx; if (ww < 0 || ww >= W_) continue;
      acc = fmaf(xz[(size_t)(bb * L_ + hh * W_ + ww) * 128 + d],
                 cw[d * 9 + (dy + 1) * 3 + (dx + 1)], acc);
    }
  }
  acc = acc / (1.f + __expf(-acc));
  xc[(size_t)(bb * L_ + idx) * DI_ + d] = acc;
}

// ---------------- D: x_dbl projection (64 -> 34 per direction), spatial order ----------------
__global__ void k_xdbl(const float* __restrict__ xc, const float* __restrict__ xpw,
                       float* __restrict__ xdbl) {
  int tile = blockIdx.x, k = blockIdx.y, bb = blockIdx.z, t = threadIdx.x;
  __shared__ float wsm[34 * 65];  // stride 65: avoid 64-stride bank conflicts
  __shared__ float xcs[16 * 64];
  for (int i = t; i < 34 * 64; i += 256) {
    int c = i >> 6, d = i & 63;
    wsm[c * 65 + d] = xpw[(k * 34 + c) * 64 + d];
  }
  int idx0 = tile * 16;
  for (int i = t; i < 16 * 64; i += 256)
    xcs[i] = xc[(size_t)(bb * L_ + idx0) * 64 + i];
  __syncthreads();
  for (int o = t; o < 16 * 34; o += 256) {
    int p = o / 34, c = o % 34;
    float acc = 0.f;
#pragma unroll
    for (int j = 0; j < 64; j++) acc = fmaf(xcs[p * 64 + j], wsm[c * 65 + j], acc);
    xdbl[((size_t)(bb * K_ + k) * L_ + idx0 + p) * 34 + c] = acc;
  }
}

// ---------------- zero fill ----------------
__global__ void k_zero(float* __restrict__ p, int n) {
  int t = blockIdx.x * 256 + threadIdx.x;
  if (t < n) p[t] = 0.f;
}

DEV float softplusf(float x) { return x > 15.f ? x : __logf(1.f + __expf(x)); }

// ---------------- E: scan phase 1 — per-chunk local state (h0=0) + sum(dt) ----------------
__global__ void k_scan1(const float* __restrict__ xdbl, const float* __restrict__ xc,
                        const float* __restrict__ dtw, const float* __restrict__ dtb,
                        const float* __restrict__ alog,
                        float* __restrict__ hbuf, float* __restrict__ ssum) {
  int chunk = blockIdx.x, k = blockIdx.y, bb = blockIdx.z, d = threadIdx.x;
  float w0 = dtw[(k * DI_ + d) * 2 + 0], w1 = dtw[(k * DI_ + d) * 2 + 1];
  float bia = dtb[k * DI_ + d];
  float A[N_], h[N_];
#pragma unroll
  for (int n = 0; n < N_; n++) { A[n] = -__expf(alog[(k * DI_ + d) * N_ + n]); h[n] = 0.f; }
  float S = 0.f;
  const float* xdb = xdbl + (size_t)(bb * K_ + k) * L_ * 34;
  const float* xcb = xc + (size_t)bb * L_ * DI_;
  for (int s = 0; s < CL_; s++) {
    int idx = map_dir(k, chunk * CL_ + s);
    const float* p = xdb + (size_t)idx * 34;
    float t0 = p[0], t1 = p[1];
    float u = xcb[(size_t)idx * DI_ + d];
    float dt = softplusf(fmaf(t0, w0, fmaf(t1, w1, bia)));
    S += dt;
    float du = dt * u;
#pragma unroll
    for (int n = 0; n < N_; n++)
      h[n] = fmaf(__expf(dt * A[n]), h[n], du * p[2 + n]);
  }
  size_t base = (size_t)((bb * K_ + k) * CH_ + chunk) * DI_ + d;
  ssum[base] = S;
#pragma unroll
  for (int n = 0; n < N_; n++) hbuf[base * N_ + n] = h[n];
}

// ---------------- F: scan phase 2 — exclusive scan over chunk summaries ----------------
__global__ void k_scan2(const float* __restrict__ alog, const float* __restrict__ ssum,
                        float* __restrict__ hbuf) {
  int t = blockIdx.x * 256 + threadIdx.x;
  if (t >= BB_ * K_ * DI_ * N_) return;
  int n = t & 15, d = (t >> 4) & 63, k = (t >> 10) & 3, bb = t >> 12;
  float A = -__expf(alog[(k * DI_ + d) * N_ + n]);
  float hp = 0.f;
  for (int c = 0; c < CH_; c++) {
    size_t sb = (size_t)((bb * K_ + k) * CH_ + c) * DI_ + d;
    float hl = hbuf[sb * N_ + n];
    float S = ssum[sb];
    hbuf[sb * N_ + n] = hp;             // overwrite with exclusive-prefix initial state
    hp = fmaf(__expf(A * S), hp, hl);
  }
}

// ---------------- G: scan phase 3 — replay with true init, emit y (+D*u) into ysum ----------------
__global__ void k_scan3(const float* __restrict__ xdbl, const float* __restrict__ xc,
                        const float* __restrict__ dtw, const float* __restrict__ dtb,
                        const float* __restrict__ alog, const float* __restrict__ Dsw,
                        const float* __restrict__ hbuf, float* __restrict__ ysum) {
  int chunk = blockIdx.x, k = blockIdx.y, bb = blockIdx.z, d = threadIdx.x;
  float w0 = dtw[(k * DI_ + d) * 2 + 0], w1 = dtw[(k * DI_ + d) * 2 + 1];
  float bia = dtb[k * DI_ + d];
  float Dk = Dsw[k * DI_ + d];
  float A[N_], h[N_];
  size_t base = (size_t)((bb * K_ + k) * CH_ + chunk) * DI_ + d;
#pragma unroll
  for (int n = 0; n < N_; n++) {
    A[n] = -__expf(alog[(k * DI_ + d) * N_ + n]);
    h[n] = hbuf[base * N_ + n];
  }
  const float* xdb = xdbl + (size_t)(bb * K_ + k) * L_ * 34;
  const float* xcb = xc + (size_t)bb * L_ * DI_;
  float* yb = ysum + (size_t)bb * L_ * DI_;
  for (int s = 0; s < CL_; s++) {
    int idx = map_dir(k, chunk * CL_ + s);
    const float* p = xdb + (size_t)idx * 34;
    float t0 = p[0], t1 = p[1];
    float u = xcb[(size_t)idx * DI_ + d];
    float dt = softplusf(fmaf(t0, w0, fmaf(t1, w1, bia)));
    float du = dt * u;
    float y = 0.f;
#pragma unroll
    for (int n = 0; n < N_; n++) {
      h[n] = fmaf(__expf(dt * A[n]), h[n], du * p[2 + n]);
      y = fmaf(h[n], p[18 + n], y);
    }
    y = fmaf(Dk, u, y);
    atomicAdd(&yb[(size_t)idx * DI_ + d], y);
  }
}

// ---------------- H: LN(64) * silu(z), out_proj (64->32), residual -> xm (B,C,L) ----------------
__global__ void k_combine(const float* __restrict__ ysum, const float* __restrict__ xz,
                          const float* __restrict__ xd, const float* __restrict__ onw,
                          const float* __restrict__ onb, const float* __restrict__ outw,
                          const float* __restrict__ mssc, float* __restrict__ xm) {
  int idx = blockIdx.x, bb = blockIdx.y, d = threadIdx.x;
  int b = bb & 1, co = (bb >> 1) * HD_;
  float y = ysum[(size_t)(bb * L_ + idx) * DI_ + d];
  float s = y, sq = y * y;
#pragma unroll
  for (int m = 1; m < 64; m <<= 1) { s += __shfl_xor(s, m, 64); sq += __shfl_xor(sq, m, 64); }
  float mean = s * (1.f / DI_);
  float var = sq * (1.f / DI_) - mean * mean;
  float rstd = rsqrtf(var + EPSF);
  float yn = (y - mean) * rstd * onw[d] + onb[d];
  float z = xz[(size_t)(bb * L_ + idx) * 128 + 64 + d];
  float g = yn * (z / (1.f + __expf(-z)));
  __shared__ float gs[DI_];
  gs[d] = g;
  __syncthreads();
  if (d < HD_) {
    float acc = 0.f;
#pragma unroll
    for (int dd = 0; dd < DI_; dd++) acc = fmaf(gs[dd], outw[dd * HD_ + d], acc);
    size_t xi = (size_t)(b * C_ + co + d) * L_ + idx;
    float xp = xd[xi];
    xm[xi] = mssc[0] * xp + xp + acc;  // ms_scale*xp + (xp + y@out_w)
  }
}

// ---------------- I: instance-norm stats over spatial for xm ----------------
__global__ void k_instats(const float* __restrict__ xm, float* __restrict__ inm,
                          float* __restrict__ inr) {
  int bc = blockIdx.x, t = threadIdx.x;
  const float* p = xm + (size_t)bc * L_;
  float s = 0.f, sq = 0.f;
  for (int i = t; i < L_; i += 256) { float v = p[i]; s += v; sq = fmaf(v, v, sq); }
  __shared__ float red[8];
#pragma unroll
  for (int m = 1; m < 64; m <<= 1) { s += __shfl_xor(s, m, 64); sq += __shfl_xor(sq, m, 64); }
  int wid = t >> 6;
  if ((t & 63) == 0) { red[wid] = s; red[4 + wid] = sq; }
  __syncthreads();
  if (t == 0) {
    s = red[0] + red[1] + red[2] + red[3];
    sq = red[4] + red[5] + red[6] + red[7];
    float mean = s * (1.f / L_);
    float var = sq * (1.f / L_) - mean * mean;
    inm[bc] = mean;
    inr[bc] = rsqrtf(var + EPSF);
  }
}

// ---------------- J: global mean+max pool of original x ----------------
__global__ void k_xpool(const float* __restrict__ x, float* __restrict__ xmean,
                        float* __restrict__ xmax) {
  int bc = blockIdx.x, t = threadIdx.x;
  const float* p = x + (size_t)bc * L_;
  float s = 0.f, mx = -1e30f;
  for (int i = t; i < L_; i += 256) { float v = p[i]; s += v; mx = fmaxf(mx, v); }
  __shared__ float red[8];
#pragma unroll
  for (int m = 1; m < 64; m <<= 1) { s += __shfl_xor(s, m, 64); mx = fmaxf(mx, __shfl_xor(mx, m, 64)); }
  int wid = t >> 6;
  if ((t & 63) == 0) { red[wid] = s; red[4 + wid] = mx; }
  __syncthreads();
  if (t == 0) {
    s = red[0] + red[1] + red[2] + red[3];
    mx = fmaxf(fmaxf(red[4], red[5]), fmaxf(red[6], red[7]));
    xmean[bc] = s * (1.f / L_);
    xmax[bc] = mx;
  }
}

// ---------------- K: gate = sigmoid(center-tap 3x3 conv on 1x1 pooled map) ----------------
__global__ void k_gate(const float* __restrict__ xmean, const float* __restrict__ xmax,
                       const float* __restrict__ maw, const float* __restrict__ mab,
                       float* __restrict__ gate) {
  int t = threadIdx.x;  // 128 = B*C
  int b = t >> 6, oc = t & 63;
  float acc = mab[oc];
  for (int ic = 0; ic < C_; ic++) {
    acc = fmaf(xmean[b * C_ + ic], maw[(oc * 128 + ic) * 9 + 4], acc);
    acc = fmaf(xmax[b * C_ + ic], maw[(oc * 128 + 64 + ic) * 9 + 4], acc);
  }
  gate[t] = 1.f / (1.f + __expf(-acc));
}

// ---------------- L: instance-norm apply + leaky_relu + gate*x -> xs2 ----------------
__global__ void k_xs(const float* __restrict__ xm, const float* __restrict__ inm,
                     const float* __restrict__ inr, const float* __restrict__ msw,
                     const float* __restrict__ msb, const float* __restrict__ gate,
                     const float* __restrict__ x, float* __restrict__ xs2) {
  int t = blockIdx.x * 256 + threadIdx.x;
  if (t >= B_ * C_ * L_) return;
  int bc = t / L_, c = bc & 63;
  float v = xm[t];
  v = (v - inm[bc]) * inr[bc] * msw[c] + msb[c];
  v = v > 0.f ? v : 0.01f * v;
  xs2[t] = v + gate[bc] * x[t];
}

// ---------------- M: axial dw convs + BN + relu -> skip ----------------
__global__ void k_axbn(const float* __restrict__ xs2, const float* __restrict__ hw,
                       const float* __restrict__ hb, const float* __restrict__ wwt,
                       const float* __restrict__ wb, const float* __restrict__ bnw,
                       const float* __restrict__ bnb, const float* __restrict__ bnm,
                       const float* __restrict__ bnv, float* __restrict__ skipf,
                       float* __restrict__ skipo) {
  int t = blockIdx.x * 256 + threadIdx.x;
  if (t >= B_ * C_ * L_) return;
  int wi = t % W_, hi = (t / W_) % H_, c = (t / L_) % C_;
  float a = xs2[t];
  float hacc = hb[c];
#pragma unroll
  for (int dy = -1; dy <= 1; dy++) {
    int hh = hi + dy; if (hh < 0 || hh >= H_) continue;
    hacc = fmaf(xs2[t + dy * W_], hw[c * 3 + dy + 1], hacc);
  }
  float wacc = wb[c];
#pragma unroll
  for (int dx = -1; dx <= 1; dx++) {
    int ww = wi + dx; if (ww < 0 || ww >= W_) continue;
    wacc = fmaf(xs2[t + dx], wwt[c * 3 + dx + 1], wacc);
  }
  float v = a + hacc + wacc;
  float sv = (v - bnm[c]) * rsqrtf(bnv[c] + EPSF) * bnw[c] + bnb[c];
  sv = fmaxf(sv, 0.f);
  skipf[t] = sv;
  skipo[t] = sv;
}

// ---------------- N: 1x1 conv (64->128) + 2x2 maxpool -> down ----------------
__global__ void k_pwpool(const float* __restrict__ skipf, const float* __restrict__ pww,
                         const float* __restrict__ pwb, float* __restrict__ down) {
  int h2 = blockIdx.x, b = blockIdx.y, t = threadIdx.x;
  __shared__ float sk[64 * 192];  // [c][r(2)][w(96)]
  for (int i = t; i < 64 * 192; i += 256) {
    int c = i / 192, rw = i % 192, r = rw / 96, wcol = rw % 96;
    sk[i] = skipf[((size_t)(b * C_ + c) * H_ + (2 * h2 + r)) * W_ + wcol];
  }
  __syncthreads();
  for (int o = t; o < OC_ * 48; o += 256) {
    int oc = o / 48, w2 = o % 48;
    float s0 = 0.f, s1 = 0.f, s2 = 0.f, s3 = 0.f;
#pragma unroll 8
    for (int c = 0; c < 64; c++) {
      float wv = pww[oc * 64 + c];
      const float* sp = &sk[c * 192 + 2 * w2];
      s0 = fmaf(sp[0], wv, s0);
      s1 = fmaf(sp[1], wv, s1);
      s2 = fmaf(sp[96], wv, s2);
      s3 = fmaf(sp[97], wv, s3);
    }
    float v = fmaxf(fmaxf(s0, s1), fmaxf(s2, s3)) + pwb[oc];
    down[((size_t)(b * OC_ + oc) * 48 + h2) * 48 + w2] = v;
  }
}

extern "C" void kernel_launch(void* const* d_in, const int* in_sizes, int n_in,
                              void* d_out, int out_size, void* d_ws, size_t ws_size,
                              hipStream_t stream) {
  const float* x     = (const float*)d_in[0];
  const float* dw33w = (const float*)d_in[1];
  const float* dw33b = (const float*)d_in[2];
  const float* msw   = (const float*)d_in[3];
  const float* msb   = (const float*)d_in[4];
  const float* mssc  = (const float*)d_in[5];
  const float* lnw   = (const float*)d_in[6];
  const float* lnb   = (const float*)d_in[7];
  const float* inw   = (const float*)d_in[8];
  const float* cw    = (const float*)d_in[9];
  const float* cb    = (const float*)d_in[10];
  const float* xpw   = (const float*)d_in[11];
  const float* dtw   = (const float*)d_in[12];
  const float* dtb   = (const float*)d_in[13];
  const float* alog  = (const float*)d_in[14];
  const float* Dsw   = (const float*)d_in[15];
  const float* onw   = (const float*)d_in[16];
  const float* onb   = (const float*)d_in[17];
  const float* outw  = (const float*)d_in[18];
  const float* maw   = (const float*)d_in[19];
  const float* mab   = (const float*)d_in[20];
  const float* ahw   = (const float*)d_in[21];
  const float* ahb   = (const float*)d_in[22];
  const float* aww   = (const float*)d_in[23];
  const float* awb   = (const float*)d_in[24];
  const float* pww   = (const float*)d_in[25];
  const float* pwb   = (const float*)d_in[26];
  const float* bnw   = (const float*)d_in[27];
  const float* bnb   = (const float*)d_in[28];
  const float* bnm   = (const float*)d_in[29];
  const float* bnv   = (const float*)d_in[30];

  float* ws = (float*)d_ws;
  float* xd   = ws;                  // B*C*L          = 1179648
  float* xz   = xd + 1179648;        // BB*L*128       = 4718592
  float* xc   = xz + 4718592;        // BB*L*64        = 2359296
  float* xdbl = xc + 2359296;        // BB*K*L*34      = 5013504
  float* hbuf = xdbl + 5013504;      // BB*K*CH*DI*N   = 1572864
  float* ssum = hbuf + 1572864;      // BB*K*CH*DI     = 98304
  float* ysum = ssum + 98304;        // BB*L*DI        = 2359296
  float* xm   = ysum + 2359296;      // B*C*L          = 1179648
  float* st   = xm + 1179648;        // stats: 640
  float* inm = st, * inr = st + 128, * xmean = st + 256, * xmaxv = st + 384, * gate = st + 512;
  float* xs2  = st + 640;            // B*C*L          = 1179648
  float* skipf = xm;                 // reuse xm after k_xs

  float* outp = (float*)d_out;
  float* down = outp;
  float* skipo = outp + DOWN_SZ;

  dim3 b64(64), b256(256);
  int nEl = B_ * C_ * L_;

  k_dw33<<<dim3((nEl + 255) / 256), b256, 0, stream>>>(x, dw33w, dw33b, xd);
  k_ln_inproj<<<dim3(L_, BB_), b64, 0, stream>>>(xd, lnw, lnb, inw, xz);
  k_dwsilu<<<dim3(L_, BB_), b64, 0, stream>>>(xz, cw, cb, xc);
  k_xdbl<<<dim3(L_ / 16, K_, BB_), b256, 0, stream>>>(xc, xpw, xdbl);
  k_zero<<<dim3((BB_ * L_ * DI_ + 255) / 256), b256, 0, stream>>>(ysum, BB_ * L_ * DI_);
  k_scan1<<<dim3(CH_, K_, BB_), b64, 0, stream>>>(xdbl, xc, dtw, dtb, alog, hbuf, ssum);
  k_scan2<<<dim3((BB_ * K_ * DI_ * N_ + 255) / 256), b256, 0, stream>>>(alog, ssum, hbuf);
  k_scan3<<<dim3(CH_, K_, BB_), b64, 0, stream>>>(xdbl, xc, dtw, dtb, alog, Dsw, hbuf, ysum);
  k_combine<<<dim3(L_, BB_), b64, 0, stream>>>(ysum, xz, xd, onw, onb, outw, mssc, xm);
  k_instats<<<dim3(B_ * C_), b256, 0, stream>>>(xm, inm, inr);
  k_xpool<<<dim3(B_ * C_), b256, 0, stream>>>(x, xmean, xmaxv);
  k_gate<<<dim3(1), dim3(128), 0, stream>>>(xmean, xmaxv, maw, mab, gate);
  k_xs<<<dim3((nEl + 255) / 256), b256, 0, stream>>>(xm, inm, inr, msw, msb, gate, x, xs2);
  k_axbn<<<dim3((nEl + 255) / 256), b256, 0, stream>>>(xs2, ahw, ahb, aww, awb, bnw, bnb, bnm, bnv, skipf, skipo);
  k_pwpool<<<dim3(48, B_), b256, 0, stream>>>(skipf, pww, pwb, down);
}

// Round 3
// 454.852 us; speedup vs baseline: 1.0581x; 1.0581x over previous
//
#include <hip/hip_runtime.h>
#include <hip/hip_bf16.h>

typedef __hip_bfloat16 bf16;
#define DEV __device__ __forceinline__

constexpr int B_ = 2, C_ = 64, H_ = 96, W_ = 96, L_ = 9216;
constexpr int HD_ = 32, DI_ = 64, N_ = 16, K_ = 4, BB_ = 4;
constexpr int OC_ = 128;
constexpr int CH_ = 384, CL_ = 24;          // scan chunking: 384 chunks of 24 steps
constexpr float EPSF = 1e-5f;
constexpr int DOWN_SZ = B_ * OC_ * 48 * 48; // 589824

DEV float softplusf(float x) { return x > 15.f ? x : __logf(1.f + __expf(x)); }
DEV float b2f(bf16 v) { return __bfloat162float(v); }

// per-chunk scan addressing: spatial idx = idx0 + s*stride, s in [0,CL)
// (CL=24 divides H=96, so the transposed directions never wrap a row inside a chunk)
DEV void chunk_addr(int k, int chunk, int& idx0, int& stride) {
  int r4 = chunk & 3, q = chunk >> 2;
  if (k == 0)      { idx0 = chunk * CL_;                        stride = 1;   }
  else if (k == 1) { idx0 = (24 * r4) * 96 + q;                 stride = 96;  }
  else if (k == 2) { idx0 = L_ - 1 - chunk * CL_;               stride = -1;  }
  else             { idx0 = (95 - 24 * r4) * 96 + (95 - q);     stride = -96; }
}

// ---------------- A: depthwise 3x3 (x -> xd, f32) ----------------
__global__ void k_dw33(const float* __restrict__ x, const float* __restrict__ w,
                       const float* __restrict__ bias, float* __restrict__ out) {
  int t = blockIdx.x * 256 + threadIdx.x;
  if (t >= B_ * C_ * L_) return;
  int wi = t % W_, hi = (t / W_) % H_, c = (t / L_) % C_;
  float acc = bias[c];
#pragma unroll
  for (int dy = -1; dy <= 1; dy++) {
    int hh = hi + dy; if (hh < 0 || hh >= H_) continue;
#pragma unroll
    for (int dx = -1; dx <= 1; dx++) {
      int ww = wi + dx; if (ww < 0 || ww >= W_) continue;
      acc = fmaf(x[t + dy * W_ + dx], w[c * 9 + (dy + 1) * 3 + (dx + 1)], acc);
    }
  }
  out[t] = acc;
}

// ---------------- B: LayerNorm(32) + in_proj (32->128), 64-idx tile GEMM ----------------
__global__ __launch_bounds__(256, 4) void k_ln_inproj(
    const float* __restrict__ xd, const float* __restrict__ lnw,
    const float* __restrict__ lnb, const float* __restrict__ inw,
    float* __restrict__ xzA, float* __restrict__ xzB) {
  int bb = blockIdx.y, t = threadIdx.x;
  int b = bb & 1, co = (bb >> 1) * HD_;
  int idx0 = blockIdx.x * 64;
  __shared__ float xds[32 * 68];   // [c][idx] stride 68 (16B-aligned rows for float4)
  __shared__ float meanA[64], rstdA[64];
  int lane = t & 63;
  for (int r = 0; r < 8; r++) {
    int c = r * 4 + (t >> 6);
    xds[c * 68 + lane] = xd[(size_t)(b * C_ + co + c) * L_ + idx0 + lane];
  }
  __syncthreads();
  if (t < 64) {
    float s = 0.f, sq = 0.f;
#pragma unroll
    for (int c = 0; c < 32; c++) { float v = xds[c * 68 + t]; s += v; sq = fmaf(v, v, sq); }
    float mean = s * (1.f / HD_);
    float var = sq * (1.f / HD_) - mean * mean;
    meanA[t] = mean; rstdA[t] = rsqrtf(var + EPSF);
  }
  __syncthreads();
  for (int i = t; i < 2048; i += 256) {
    int c = i >> 6, idx = i & 63;
    float v = xds[c * 68 + idx];
    xds[c * 68 + idx] = (v - meanA[idx]) * rstdA[idx] * lnw[c] + lnb[c];
  }
  __syncthreads();
  int oc = t & 127, g = t >> 7;      // g uniform per wave
  float acc[32];
#pragma unroll
  for (int j = 0; j < 32; j++) acc[j] = 0.f;
  for (int c = 0; c < 32; c++) {
    float wv = inw[c * 128 + oc];
    const float4* row = reinterpret_cast<const float4*>(&xds[c * 68 + g * 32]);
#pragma unroll
    for (int j4 = 0; j4 < 8; j4++) {
      float4 xv = row[j4];
      acc[j4 * 4 + 0] = fmaf(xv.x, wv, acc[j4 * 4 + 0]);
      acc[j4 * 4 + 1] = fmaf(xv.y, wv, acc[j4 * 4 + 1]);
      acc[j4 * 4 + 2] = fmaf(xv.z, wv, acc[j4 * 4 + 2]);
      acc[j4 * 4 + 3] = fmaf(xv.w, wv, acc[j4 * 4 + 3]);
    }
  }
  float* dst = (oc < 64) ? xzA : xzB;
  int occ = oc & 63;
#pragma unroll
  for (int j = 0; j < 32; j++) {
    int idx = g * 32 + j;
    dst[(size_t)(bb * L_ + idx0 + idx) * 64 + occ] = acc[j];
  }
}

// ---------------- C: depthwise 3x3 + SiLU -> xc (BB,L,64) ----------------
__global__ void k_dwsilu(const float* __restrict__ xzA, const float* __restrict__ cw,
                         const float* __restrict__ cb, float* __restrict__ xc) {
  int t = blockIdx.x * 256 + threadIdx.x;
  int d = t & 63, idx = (t >> 6) % L_, bb = t / (L_ * DI_);
  int wi = idx % W_, hi = idx / W_;
  float acc = cb[d];
#pragma unroll
  for (int dy = -1; dy <= 1; dy++) {
    int hh = hi + dy; if (hh < 0 || hh >= H_) continue;
#pragma unroll
    for (int dx = -1; dx <= 1; dx++) {
      int ww = wi + dx; if (ww < 0 || ww >= W_) continue;
      acc = fmaf(xzA[(size_t)(bb * L_ + hh * W_ + ww) * 64 + d],
                 cw[d * 9 + (dy + 1) * 3 + (dx + 1)], acc);
    }
  }
  acc = acc / (1.f + __expf(-acc));
  xc[t] = acc;
}

// ---------------- D: x_dbl projection (64 -> 34 per direction) ----------------
__global__ void k_xdbl(const float* __restrict__ xc, const float* __restrict__ xpw,
                       float* __restrict__ xdbl) {
  int tile = blockIdx.x, k = blockIdx.y, bb = blockIdx.z, t = threadIdx.x;
  __shared__ float wsm[34 * 65];
  __shared__ float xcs[16 * 64];
  for (int i = t; i < 34 * 64; i += 256) {
    int c = i >> 6, d = i & 63;
    wsm[c * 65 + d] = xpw[(k * 34 + c) * 64 + d];
  }
  int idx0 = tile * 16;
  for (int i = t; i < 16 * 64; i += 256)
    xcs[i] = xc[(size_t)(bb * L_ + idx0) * 64 + i];
  __syncthreads();
  for (int o = t; o < 16 * 34; o += 256) {
    int p = o / 34, c = o % 34;
    float acc = 0.f;
#pragma unroll
    for (int j = 0; j < 64; j++) acc = fmaf(xcs[p * 64 + j], wsm[c * 65 + j], acc);
    xdbl[((size_t)(bb * K_ + k) * L_ + idx0 + p) * 34 + c] = acc;
  }
}

// ---------------- E: scan phase 1 — per-chunk local state (h0=0) + sum(dt) ----------------
__global__ __launch_bounds__(256, 4) void k_scan1(
    const float* __restrict__ xdbl, const float* __restrict__ xc,
    const float* __restrict__ dtw, const float* __restrict__ dtb,
    const float* __restrict__ alog, bf16* __restrict__ hbuf,
    float* __restrict__ ssum, float* __restrict__ ysum) {
  int w = threadIdx.x >> 6, d = threadIdx.x & 63;
  int chunk = blockIdx.x * 4 + w, k = blockIdx.y, bb = blockIdx.z;
  if (k == 0) {  // zero ysum slice (this kernel runs before scan3's atomics)
    float* yb = ysum + ((size_t)bb * L_ + chunk * CL_) * DI_ + d;
#pragma unroll
    for (int j = 0; j < CL_; j++) yb[j * DI_] = 0.f;
  }
  float w0 = dtw[(k * DI_ + d) * 2 + 0], w1 = dtw[(k * DI_ + d) * 2 + 1];
  float bia = dtb[k * DI_ + d];
  float A[N_], h[N_];
#pragma unroll
  for (int n = 0; n < N_; n++) { A[n] = -__expf(alog[(k * DI_ + d) * N_ + n]); h[n] = 0.f; }
  int idx0, stride;
  chunk_addr(k, chunk, idx0, stride);
  const float* xdb = xdbl + (size_t)(bb * K_ + k) * L_ * 34;
  const float* xcb = xc + (size_t)bb * L_ * DI_;
  float S = 0.f;
  int idx = idx0;
  float t0 = xdb[(size_t)idx * 34], t1 = xdb[(size_t)idx * 34 + 1];
  float u = xcb[(size_t)idx * DI_ + d];
  for (int s = 0; s < CL_; s++) {
    int nidx = (s + 1 < CL_) ? idx + stride : idx0;   // pad-read last iter
    float nt0 = xdb[(size_t)nidx * 34], nt1 = xdb[(size_t)nidx * 34 + 1];
    float nu = xcb[(size_t)nidx * DI_ + d];
    const float* p = xdb + (size_t)idx * 34;
    float dt = softplusf(fmaf(t0, w0, fmaf(t1, w1, bia)));
    S += dt;
    float du = dt * u;
#pragma unroll
    for (int n = 0; n < N_; n++)
      h[n] = fmaf(__expf(dt * A[n]), h[n], du * p[2 + n]);
    idx = nidx; t0 = nt0; t1 = nt1; u = nu;
  }
  size_t base = (size_t)((bb * K_ + k) * CH_ + chunk) * DI_ + d;
  ssum[base] = S;
#pragma unroll
  for (int n = 0; n < N_; n++) hbuf[base * N_ + n] = __float2bfloat16(h[n]);
}

// ---------------- F: scan phase 2 — exclusive scan over chunk summaries ----------------
__global__ void k_scan2(const float* __restrict__ alog, const float* __restrict__ ssum,
                        bf16* __restrict__ hbuf) {
  int t = blockIdx.x * 256 + threadIdx.x;
  int n = t & 15, d = (t >> 4) & 63, k = (t >> 10) & 3, bb = t >> 12;
  float A = -__expf(alog[(k * DI_ + d) * N_ + n]);
  size_t row = (size_t)(bb * K_ + k) * CH_ * DI_ + d;  // + c*DI_
  float hp = 0.f;
  for (int c = 0; c < CH_; c += 4) {
    size_t s0 = row + (size_t)c * DI_;
    float S0 = ssum[s0], S1 = ssum[s0 + DI_], S2 = ssum[s0 + 2 * DI_], S3 = ssum[s0 + 3 * DI_];
    float h0 = b2f(hbuf[s0 * N_ + n]), h1 = b2f(hbuf[(s0 + DI_) * N_ + n]);
    float h2 = b2f(hbuf[(s0 + 2 * DI_) * N_ + n]), h3 = b2f(hbuf[(s0 + 3 * DI_) * N_ + n]);
    float e0 = __expf(A * S0), e1 = __expf(A * S1), e2 = __expf(A * S2), e3 = __expf(A * S3);
    hbuf[s0 * N_ + n] = __float2bfloat16(hp);             hp = fmaf(e0, hp, h0);
    hbuf[(s0 + DI_) * N_ + n] = __float2bfloat16(hp);     hp = fmaf(e1, hp, h1);
    hbuf[(s0 + 2 * DI_) * N_ + n] = __float2bfloat16(hp); hp = fmaf(e2, hp, h2);
    hbuf[(s0 + 3 * DI_) * N_ + n] = __float2bfloat16(hp); hp = fmaf(e3, hp, h3);
  }
}

// ---------------- G: scan phase 3 — replay with true init, emit y into ysum ----------------
__global__ __launch_bounds__(256, 4) void k_scan3(
    const float* __restrict__ xdbl, const float* __restrict__ xc,
    const float* __restrict__ dtw, const float* __restrict__ dtb,
    const float* __restrict__ alog, const float* __restrict__ Dsw,
    const bf16* __restrict__ hbuf, float* __restrict__ ysum) {
  int w = threadIdx.x >> 6, d = threadIdx.x & 63;
  int chunk = blockIdx.x * 4 + w, k = blockIdx.y, bb = blockIdx.z;
  float w0 = dtw[(k * DI_ + d) * 2 + 0], w1 = dtw[(k * DI_ + d) * 2 + 1];
  float bia = dtb[k * DI_ + d];
  float Dk = Dsw[k * DI_ + d];
  float A[N_], h[N_];
  size_t base = (size_t)((bb * K_ + k) * CH_ + chunk) * DI_ + d;
#pragma unroll
  for (int n = 0; n < N_; n++) {
    A[n] = -__expf(alog[(k * DI_ + d) * N_ + n]);
    h[n] = b2f(hbuf[base * N_ + n]);
  }
  int idx0, stride;
  chunk_addr(k, chunk, idx0, stride);
  const float* xdb = xdbl + (size_t)(bb * K_ + k) * L_ * 34;
  const float* xcb = xc + (size_t)bb * L_ * DI_;
  float* yb = ysum + (size_t)bb * L_ * DI_;
  int idx = idx0;
  float t0 = xdb[(size_t)idx * 34], t1 = xdb[(size_t)idx * 34 + 1];
  float u = xcb[(size_t)idx * DI_ + d];
  for (int s = 0; s < CL_; s++) {
    int nidx = (s + 1 < CL_) ? idx + stride : idx0;
    float nt0 = xdb[(size_t)nidx * 34], nt1 = xdb[(size_t)nidx * 34 + 1];
    float nu = xcb[(size_t)nidx * DI_ + d];
    const float* p = xdb + (size_t)idx * 34;
    float dt = softplusf(fmaf(t0, w0, fmaf(t1, w1, bia)));
    float du = dt * u;
    float y = 0.f;
#pragma unroll
    for (int n = 0; n < N_; n++) {
      h[n] = fmaf(__expf(dt * A[n]), h[n], du * p[2 + n]);
      y = fmaf(h[n], p[18 + n], y);
    }
    y = fmaf(Dk, u, y);
    atomicAdd(&yb[(size_t)idx * DI_ + d], y);
    idx = nidx; t0 = nt0; t1 = nt1; u = nu;
  }
}

// ---------------- H: LN(64)*silu(z), out_proj (64->32), residual -> xm ----------------
__global__ void k_combine(const float* __restrict__ ysum, const float* __restrict__ xzB,
                          const float* __restrict__ xd, const float* __restrict__ onw,
                          const float* __restrict__ onb, const float* __restrict__ outw,
                          const float* __restrict__ mssc, float* __restrict__ xm) {
  int w = threadIdx.x >> 6, d = threadIdx.x & 63;
  int idx = blockIdx.x * 4 + w, bb = blockIdx.y;
  int b = bb & 1, co = (bb >> 1) * HD_;
  float y = ysum[(size_t)(bb * L_ + idx) * DI_ + d];
  float s = y, sq = y * y;
#pragma unroll
  for (int m = 1; m < 64; m <<= 1) { s += __shfl_xor(s, m, 64); sq += __shfl_xor(sq, m, 64); }
  float mean = s * (1.f / DI_);
  float var = sq * (1.f / DI_) - mean * mean;
  float rstd = rsqrtf(var + EPSF);
  float yn = (y - mean) * rstd * onw[d] + onb[d];
  float z = xzB[(size_t)(bb * L_ + idx) * 64 + d];
  float g = yn * (z / (1.f + __expf(-z)));
  __shared__ float gs[4][DI_];
  gs[w][d] = g;
  __syncthreads();
  if (d < HD_) {
    float acc = 0.f;
#pragma unroll
    for (int dd = 0; dd < DI_; dd++) acc = fmaf(gs[w][dd], outw[dd * HD_ + d], acc);
    size_t xi = (size_t)(b * C_ + co + d) * L_ + idx;
    float xp = xd[xi];
    xm[xi] = mssc[0] * xp + xp + acc;
  }
}

// ---------------- I: fused instance-norm stats (xm) + global mean/max pool (x) ----------------
__global__ void k_stats(const float* __restrict__ xm, const float* __restrict__ x,
                        float* __restrict__ inm, float* __restrict__ inr,
                        float* __restrict__ xmean, float* __restrict__ xmax) {
  int bc = blockIdx.x, t = threadIdx.x;
  const float* pm = xm + (size_t)bc * L_;
  const float* px = x + (size_t)bc * L_;
  float s = 0.f, sq = 0.f, xs = 0.f, mx = -1e30f;
  for (int i = t; i < L_; i += 256) {
    float v = pm[i]; s += v; sq = fmaf(v, v, sq);
    float xv = px[i]; xs += xv; mx = fmaxf(mx, xv);
  }
  __shared__ float red[16];
#pragma unroll
  for (int m = 1; m < 64; m <<= 1) {
    s += __shfl_xor(s, m, 64); sq += __shfl_xor(sq, m, 64);
    xs += __shfl_xor(xs, m, 64); mx = fmaxf(mx, __shfl_xor(mx, m, 64));
  }
  int wid = t >> 6;
  if ((t & 63) == 0) { red[wid] = s; red[4 + wid] = sq; red[8 + wid] = xs; red[12 + wid] = mx; }
  __syncthreads();
  if (t == 0) {
    s = red[0] + red[1] + red[2] + red[3];
    sq = red[4] + red[5] + red[6] + red[7];
    xs = red[8] + red[9] + red[10] + red[11];
    mx = fmaxf(fmaxf(red[12], red[13]), fmaxf(red[14], red[15]));
    float mean = s * (1.f / L_);
    float var = sq * (1.f / L_) - mean * mean;
    inm[bc] = mean;
    inr[bc] = rsqrtf(var + EPSF);
    xmean[bc] = xs * (1.f / L_);
    xmax[bc] = mx;
  }
}

// ---------------- L: IN apply + leaky_relu + sigmoid-gate*x -> xs2 (gate inlined) ----------------
__global__ void k_xs(const float* __restrict__ xm, const float* __restrict__ inm,
                     const float* __restrict__ inr, const float* __restrict__ msw,
                     const float* __restrict__ msb, const float* __restrict__ xmean,
                     const float* __restrict__ xmax, const float* __restrict__ maw,
                     const float* __restrict__ mab, const float* __restrict__ x,
                     float* __restrict__ xs2) {
  int t = blockIdx.x * 256 + threadIdx.x;
  int bc = t / L_, c = bc & 63, b = bc >> 6;   // c uniform per block (256 | L)
  float acc = mab[c];
#pragma unroll 8
  for (int ic = 0; ic < 64; ic++) {
    acc = fmaf(xmean[b * 64 + ic], maw[(c * 128 + ic) * 9 + 4], acc);
    acc = fmaf(xmax[b * 64 + ic], maw[(c * 128 + 64 + ic) * 9 + 4], acc);
  }
  float gate = 1.f / (1.f + __expf(-acc));
  float v = xm[t];
  v = (v - inm[bc]) * inr[bc] * msw[c] + msb[c];
  v = v > 0.f ? v : 0.01f * v;
  xs2[t] = v + gate * x[t];
}

// ---------------- M: axial dw convs + BN + relu -> skip (written straight to d_out) ----------------
__global__ void k_axbn(const float* __restrict__ xs2, const float* __restrict__ hw,
                       const float* __restrict__ hb, const float* __restrict__ wwt,
                       const float* __restrict__ wb, const float* __restrict__ bnw,
                       const float* __restrict__ bnb, const float* __restrict__ bnm,
                       const float* __restrict__ bnv, float* __restrict__ skipo) {
  int t = blockIdx.x * 256 + threadIdx.x;
  if (t >= B_ * C_ * L_) return;
  int wi = t % W_, hi = (t / W_) % H_, c = (t / L_) % C_;
  float a = xs2[t];
  float hacc = hb[c];
#pragma unroll
  for (int dy = -1; dy <= 1; dy++) {
    int hh = hi + dy; if (hh < 0 || hh >= H_) continue;
    hacc = fmaf(xs2[t + dy * W_], hw[c * 3 + dy + 1], hacc);
  }
  float wacc = wb[c];
#pragma unroll
  for (int dx = -1; dx <= 1; dx++) {
    int ww = wi + dx; if (ww < 0 || ww >= W_) continue;
    wacc = fmaf(xs2[t + dx], wwt[c * 3 + dx + 1], wacc);
  }
  float v = a + hacc + wacc;
  float sv = (v - bnm[c]) * rsqrtf(bnv[c] + EPSF) * bnw[c] + bnb[c];
  skipo[t] = fmaxf(sv, 0.f);
}

// ---------------- N: 1x1 conv (64->128) + 2x2 maxpool -> down ----------------
__global__ void k_pwpool(const float* __restrict__ skipo, const float* __restrict__ pww,
                         const float* __restrict__ pwb, float* __restrict__ down) {
  int h2 = blockIdx.x, b = blockIdx.y, t = threadIdx.x;
  __shared__ float sk[64 * 192];  // [c][r(2)][w(96)]
  for (int i = t; i < 64 * 192; i += 256) {
    int c = i / 192, rw = i % 192, r = rw / 96, wcol = rw % 96;
    sk[i] = skipo[((size_t)(b * C_ + c) * H_ + (2 * h2 + r)) * W_ + wcol];
  }
  __syncthreads();
  for (int o = t; o < OC_ * 48; o += 256) {
    int oc = o / 48, w2 = o % 48;
    float s0 = 0.f, s1 = 0.f, s2 = 0.f, s3 = 0.f;
#pragma unroll 8
    for (int c = 0; c < 64; c++) {
      float wv = pww[oc * 64 + c];
      const float* sp = &sk[c * 192 + 2 * w2];
      s0 = fmaf(sp[0], wv, s0);
      s1 = fmaf(sp[1], wv, s1);
      s2 = fmaf(sp[96], wv, s2);
      s3 = fmaf(sp[97], wv, s3);
    }
    float v = fmaxf(fmaxf(s0, s1), fmaxf(s2, s3)) + pwb[oc];
    down[((size_t)(b * OC_ + oc) * 48 + h2) * 48 + w2] = v;
  }
}

extern "C" void kernel_launch(void* const* d_in, const int* in_sizes, int n_in,
                              void* d_out, int out_size, void* d_ws, size_t ws_size,
                              hipStream_t stream) {
  const float* x     = (const float*)d_in[0];
  const float* dw33w = (const float*)d_in[1];
  const float* dw33b = (const float*)d_in[2];
  const float* msw   = (const float*)d_in[3];
  const float* msb   = (const float*)d_in[4];
  const float* mssc  = (const float*)d_in[5];
  const float* lnw   = (const float*)d_in[6];
  const float* lnb   = (const float*)d_in[7];
  const float* inw   = (const float*)d_in[8];
  const float* cw    = (const float*)d_in[9];
  const float* cb    = (const float*)d_in[10];
  const float* xpw   = (const float*)d_in[11];
  const float* dtw   = (const float*)d_in[12];
  const float* dtb   = (const float*)d_in[13];
  const float* alog  = (const float*)d_in[14];
  const float* Dsw   = (const float*)d_in[15];
  const float* onw   = (const float*)d_in[16];
  const float* onb   = (const float*)d_in[17];
  const float* outw  = (const float*)d_in[18];
  const float* maw   = (const float*)d_in[19];
  const float* mab   = (const float*)d_in[20];
  const float* ahw   = (const float*)d_in[21];
  const float* ahb   = (const float*)d_in[22];
  const float* aww   = (const float*)d_in[23];
  const float* awb   = (const float*)d_in[24];
  const float* pww   = (const float*)d_in[25];
  const float* pwb   = (const float*)d_in[26];
  const float* bnw   = (const float*)d_in[27];
  const float* bnb   = (const float*)d_in[28];
  const float* bnm   = (const float*)d_in[29];
  const float* bnv   = (const float*)d_in[30];

  float* ws = (float*)d_ws;
  // layout (floats); hbuf(bf16, 6.29M elems = 3.145M slots) overlays dead xzA(2.36M)+extra
  float* xd   = ws;                     // 1,179,648
  float* xzA  = xd + 1179648;           // 2,359,296 (xp half; dead after k_dwsilu)
  bf16*  hbuf = (bf16*)xzA;             // 6,291,456 bf16 -> 3,145,728 slots
  float* xzB  = xzA + 3145728;          // 2,359,296 (z half; alive to combine)
  float* xc   = xzB + 2359296;          // 2,359,296
  float* xdbl = xc + 2359296;           // 5,013,504
  float* ssum = xdbl + 5013504;         // 393,216
  float* ysum = ssum + 393216;          // 2,359,296
  float* xm   = ysum + 2359296;         // 1,179,648
  float* xs2  = xm + 1179648;           // 1,179,648
  float* st   = xs2 + 1179648;          // 512
  float* inm = st, *inr = st + 128, *xmean = st + 256, *xmaxv = st + 384;

  float* outp = (float*)d_out;
  float* down = outp;
  float* skipo = outp + DOWN_SZ;

  dim3 b256(256);
  int nEl = B_ * C_ * L_;

  k_dw33<<<dim3((nEl + 255) / 256), b256, 0, stream>>>(x, dw33w, dw33b, xd);
  k_ln_inproj<<<dim3(L_ / 64, BB_), b256, 0, stream>>>(xd, lnw, lnb, inw, xzA, xzB);
  k_dwsilu<<<dim3(BB_ * L_ * DI_ / 256), b256, 0, stream>>>(xzA, cw, cb, xc);
  k_xdbl<<<dim3(L_ / 16, K_, BB_), b256, 0, stream>>>(xc, xpw, xdbl);
  k_scan1<<<dim3(CH_ / 4, K_, BB_), b256, 0, stream>>>(xdbl, xc, dtw, dtb, alog, hbuf, ssum, ysum);
  k_scan2<<<dim3(BB_ * K_ * DI_ * N_ / 256), b256, 0, stream>>>(alog, ssum, hbuf);
  k_scan3<<<dim3(CH_ / 4, K_, BB_), b256, 0, stream>>>(xdbl, xc, dtw, dtb, alog, Dsw, hbuf, ysum);
  k_combine<<<dim3(L_ / 4, BB_), b256, 0, stream>>>(ysum, xzB, xd, onw, onb, outw, mssc, xm);
  k_stats<<<dim3(B_ * C_), b256, 0, stream>>>(xm, x, inm, inr, xmean, xmaxv);
  k_xs<<<dim3((nEl + 255) / 256), b256, 0, stream>>>(xm, inm, inr, msw, msb, xmean, xmaxv, maw, mab, x, xs2);
  k_axbn<<<dim3((nEl + 255) / 256), b256, 0, stream>>>(xs2, ahw, ahb, aww, awb, bnw, bnb, bnm, bnv, skipo);
  k_pwpool<<<dim3(48, B_), b256, 0, stream>>>(skipo, pww, pwb, down);
}

// Round 4
// 383.490 us; speedup vs baseline: 1.2550x; 1.1861x over previous
//
#include <hip/hip_runtime.h>
#include <hip/hip_bf16.h>

typedef __hip_bfloat16 bf16;
#define DEV __device__ __forceinline__

constexpr int B_ = 2, C_ = 64, H_ = 96, W_ = 96, L_ = 9216;
constexpr int HD_ = 32, DI_ = 64, N_ = 16, K_ = 4, BB_ = 4;
constexpr int OC_ = 128;
constexpr int CH_ = 384, CL_ = 24;          // scan chunking: 384 chunks of 24 steps
constexpr float EPSF = 1e-5f;
constexpr int DOWN_SZ = B_ * OC_ * 48 * 48; // 589824

typedef __attribute__((ext_vector_type(8))) short short8;   // 8 bf16 (4 VGPRs)
typedef __attribute__((ext_vector_type(4))) float f32x4;    // MFMA accumulator

DEV float softplusf(float x) { return x > 15.f ? x : __logf(1.f + __expf(x)); }
DEV float b2f(bf16 v) { return __bfloat162float(v); }

// per-chunk scan addressing: spatial idx = idx0 + s*stride, s in [0,CL)
DEV void chunk_addr(int k, int chunk, int& idx0, int& stride) {
  int r4 = chunk & 3, q = chunk >> 2;
  if (k == 0)      { idx0 = chunk * CL_;                        stride = 1;   }
  else if (k == 1) { idx0 = (24 * r4) * 96 + q;                 stride = 96;  }
  else if (k == 2) { idx0 = L_ - 1 - chunk * CL_;               stride = -1;  }
  else             { idx0 = (95 - 24 * r4) * 96 + (95 - q);     stride = -96; }
}

// ---------------- A: depthwise 3x3 (x -> xd, f32) ----------------
__global__ void k_dw33(const float* __restrict__ x, const float* __restrict__ w,
                       const float* __restrict__ bias, float* __restrict__ out) {
  int t = blockIdx.x * 256 + threadIdx.x;
  if (t >= B_ * C_ * L_) return;
  int wi = t % W_, hi = (t / W_) % H_, c = (t / L_) % C_;
  float acc = bias[c];
#pragma unroll
  for (int dy = -1; dy <= 1; dy++) {
    int hh = hi + dy; if (hh < 0 || hh >= H_) continue;
#pragma unroll
    for (int dx = -1; dx <= 1; dx++) {
      int ww = wi + dx; if (ww < 0 || ww >= W_) continue;
      acc = fmaf(x[t + dy * W_ + dx], w[c * 9 + (dy + 1) * 3 + (dx + 1)], acc);
    }
  }
  out[t] = acc;
}

// ---------------- B: LayerNorm(32) + in_proj (32->128), 64-idx tile GEMM ----------------
__global__ __launch_bounds__(256, 4) void k_ln_inproj(
    const float* __restrict__ xd, const float* __restrict__ lnw,
    const float* __restrict__ lnb, const float* __restrict__ inw,
    float* __restrict__ xzA, float* __restrict__ xzB) {
  int bb = blockIdx.y, t = threadIdx.x;
  int b = bb & 1, co = (bb >> 1) * HD_;
  int idx0 = blockIdx.x * 64;
  __shared__ float xds[32 * 68];
  __shared__ float meanA[64], rstdA[64];
  int lane = t & 63;
  for (int r = 0; r < 8; r++) {
    int c = r * 4 + (t >> 6);
    xds[c * 68 + lane] = xd[(size_t)(b * C_ + co + c) * L_ + idx0 + lane];
  }
  __syncthreads();
  if (t < 64) {
    float s = 0.f, sq = 0.f;
#pragma unroll
    for (int c = 0; c < 32; c++) { float v = xds[c * 68 + t]; s += v; sq = fmaf(v, v, sq); }
    float mean = s * (1.f / HD_);
    float var = sq * (1.f / HD_) - mean * mean;
    meanA[t] = mean; rstdA[t] = rsqrtf(var + EPSF);
  }
  __syncthreads();
  for (int i = t; i < 2048; i += 256) {
    int c = i >> 6, idx = i & 63;
    float v = xds[c * 68 + idx];
    xds[c * 68 + idx] = (v - meanA[idx]) * rstdA[idx] * lnw[c] + lnb[c];
  }
  __syncthreads();
  int oc = t & 127, g = t >> 7;
  float acc[32];
#pragma unroll
  for (int j = 0; j < 32; j++) acc[j] = 0.f;
  for (int c = 0; c < 32; c++) {
    float wv = inw[c * 128 + oc];
    const float4* row = reinterpret_cast<const float4*>(&xds[c * 68 + g * 32]);
#pragma unroll
    for (int j4 = 0; j4 < 8; j4++) {
      float4 xv = row[j4];
      acc[j4 * 4 + 0] = fmaf(xv.x, wv, acc[j4 * 4 + 0]);
      acc[j4 * 4 + 1] = fmaf(xv.y, wv, acc[j4 * 4 + 1]);
      acc[j4 * 4 + 2] = fmaf(xv.z, wv, acc[j4 * 4 + 2]);
      acc[j4 * 4 + 3] = fmaf(xv.w, wv, acc[j4 * 4 + 3]);
    }
  }
  float* dst = (oc < 64) ? xzA : xzB;
  int occ = oc & 63;
#pragma unroll
  for (int j = 0; j < 32; j++) {
    int idx = g * 32 + j;
    dst[(size_t)(bb * L_ + idx0 + idx) * 64 + occ] = acc[j];
  }
}

// ---------------- C: depthwise 3x3 + SiLU -> xc (f32) + xch (bf16) ----------------
__global__ void k_dwsilu(const float* __restrict__ xzA, const float* __restrict__ cw,
                         const float* __restrict__ cb, float* __restrict__ xc,
                         bf16* __restrict__ xch) {
  int t = blockIdx.x * 256 + threadIdx.x;
  int d = t & 63, idx = (t >> 6) % L_, bb = t / (L_ * DI_);
  int wi = idx % W_, hi = idx / W_;
  float acc = cb[d];
#pragma unroll
  for (int dy = -1; dy <= 1; dy++) {
    int hh = hi + dy; if (hh < 0 || hh >= H_) continue;
#pragma unroll
    for (int dx = -1; dx <= 1; dx++) {
      int ww = wi + dx; if (ww < 0 || ww >= W_) continue;
      acc = fmaf(xzA[(size_t)(bb * L_ + hh * W_ + ww) * 64 + d],
                 cw[d * 9 + (dy + 1) * 3 + (dx + 1)], acc);
    }
  }
  acc = acc / (1.f + __expf(-acc));
  xc[t] = acc;
  xch[t] = __float2bfloat16(acc);
}

// ---------------- D0: weight prep — 136x64 f32 -> 144x64 bf16 (zero-padded) ----------------
__global__ void k_wprep(const float* __restrict__ xpw, bf16* __restrict__ wh) {
  int i = blockIdx.x * 256 + threadIdx.x;  // 144*64
  if (i >= 144 * 64) return;
  int n = i >> 6;
  wh[i] = __float2bfloat16(n < 136 ? xpw[i] : 0.f);
}

// ---------------- D: x_dbl projection via MFMA: [36864 x 64] @ [64 x 136] ----------------
// A-frag: A[m=lane&15][k=quad*8+j] ; B-frag: B[k=quad*8+j][n=lane&15] = W[n][k]
// D: col n = lane&15, row m = quad*4 + reg.
__global__ __launch_bounds__(256, 4) void k_xdbl_mfma(
    const bf16* __restrict__ xch, const bf16* __restrict__ wh,
    float* __restrict__ xdbl) {
  int w = threadIdx.x >> 6, lane = threadIdx.x & 63;
  int bb = blockIdx.y;
  int mtile = blockIdx.x * 4 + w;       // 16 positions per wave
  int idx0 = mtile * 16;
  int m = lane & 15, quad = lane >> 4;
  const bf16* arow = xch + ((size_t)bb * L_ + idx0 + m) * 64 + quad * 8;
  short8 a0 = *reinterpret_cast<const short8*>(arow);
  short8 a1 = *reinterpret_cast<const short8*>(arow + 32);
#pragma unroll
  for (int nt = 0; nt < 9; nt++) {
    int n = nt * 16 + m;
    const bf16* brow = wh + n * 64 + quad * 8;
    short8 b0 = *reinterpret_cast<const short8*>(brow);
    short8 b1 = *reinterpret_cast<const short8*>(brow + 32);
    f32x4 acc = {0.f, 0.f, 0.f, 0.f};
    acc = __builtin_amdgcn_mfma_f32_16x16x32_bf16(a0, b0, acc, 0, 0, 0);
    acc = __builtin_amdgcn_mfma_f32_16x16x32_bf16(a1, b1, acc, 0, 0, 0);
    if (n < 136) {
      int k4 = (n >= 102) ? 3 : (n >= 68) ? 2 : (n >= 34) ? 1 : 0;
      int c = n - k4 * 34;
      float* dst = xdbl + ((size_t)(bb * K_ + k4) * L_ + idx0 + quad * 4) * 34 + c;
      dst[0] = acc[0]; dst[34] = acc[1]; dst[68] = acc[2]; dst[102] = acc[3];
    }
  }
}

// ---------------- E: scan phase 1 — per-chunk local state (h0=0) + sum(dt) ----------------
__global__ __launch_bounds__(256, 4) void k_scan1(
    const float* __restrict__ xdbl, const float* __restrict__ xc,
    const float* __restrict__ dtw, const float* __restrict__ dtb,
    const float* __restrict__ alog, bf16* __restrict__ hbuf,
    float* __restrict__ ssum, float* __restrict__ ysum) {
  int w = threadIdx.x >> 6, d = threadIdx.x & 63;
  int chunk = blockIdx.x * 4 + w, k = blockIdx.y, bb = blockIdx.z;
  if (k == 0) {  // zero ysum slice before scan3's atomics
    float* yb = ysum + ((size_t)bb * L_ + chunk * CL_) * DI_ + d;
#pragma unroll
    for (int j = 0; j < CL_; j++) yb[j * DI_] = 0.f;
  }
  float w0 = dtw[(k * DI_ + d) * 2 + 0], w1 = dtw[(k * DI_ + d) * 2 + 1];
  float bia = dtb[k * DI_ + d];
  float A[N_], h[N_];
#pragma unroll
  for (int n = 0; n < N_; n++) { A[n] = -__expf(alog[(k * DI_ + d) * N_ + n]); h[n] = 0.f; }
  int idx0, stride;
  chunk_addr(k, chunk, idx0, stride);
  const float* xdb = xdbl + (size_t)(bb * K_ + k) * L_ * 34;
  const float* xcb = xc + (size_t)bb * L_ * DI_;
  float S = 0.f;
  int idx = idx0;
  float t0 = xdb[(size_t)idx * 34], t1 = xdb[(size_t)idx * 34 + 1];
  float u = xcb[(size_t)idx * DI_ + d];
  for (int s = 0; s < CL_; s++) {
    int nidx = (s + 1 < CL_) ? idx + stride : idx0;
    float nt0 = xdb[(size_t)nidx * 34], nt1 = xdb[(size_t)nidx * 34 + 1];
    float nu = xcb[(size_t)nidx * DI_ + d];
    const float* p = xdb + (size_t)idx * 34;
    float dt = softplusf(fmaf(t0, w0, fmaf(t1, w1, bia)));
    S += dt;
    float du = dt * u;
#pragma unroll
    for (int n = 0; n < N_; n++)
      h[n] = fmaf(__expf(dt * A[n]), h[n], du * p[2 + n]);
    idx = nidx; t0 = nt0; t1 = nt1; u = nu;
  }
  size_t base = (size_t)((bb * K_ + k) * CH_ + chunk) * DI_ + d;
  ssum[base] = S;
#pragma unroll
  for (int n = 0; n < N_; n++) hbuf[base * N_ + n] = __float2bfloat16(h[n]);
}

// ---------------- F: scan phase 2 — exclusive scan over chunk summaries ----------------
__global__ void k_scan2(const float* __restrict__ alog, const float* __restrict__ ssum,
                        bf16* __restrict__ hbuf) {
  int t = blockIdx.x * 256 + threadIdx.x;
  int n = t & 15, d = (t >> 4) & 63, k = (t >> 10) & 3, bb = t >> 12;
  float A = -__expf(alog[(k * DI_ + d) * N_ + n]);
  size_t row = (size_t)(bb * K_ + k) * CH_ * DI_ + d;
  float hp = 0.f;
  for (int c = 0; c < CH_; c += 4) {
    size_t s0 = row + (size_t)c * DI_;
    float S0 = ssum[s0], S1 = ssum[s0 + DI_], S2 = ssum[s0 + 2 * DI_], S3 = ssum[s0 + 3 * DI_];
    float h0 = b2f(hbuf[s0 * N_ + n]), h1 = b2f(hbuf[(s0 + DI_) * N_ + n]);
    float h2 = b2f(hbuf[(s0 + 2 * DI_) * N_ + n]), h3 = b2f(hbuf[(s0 + 3 * DI_) * N_ + n]);
    float e0 = __expf(A * S0), e1 = __expf(A * S1), e2 = __expf(A * S2), e3 = __expf(A * S3);
    hbuf[s0 * N_ + n] = __float2bfloat16(hp);             hp = fmaf(e0, hp, h0);
    hbuf[(s0 + DI_) * N_ + n] = __float2bfloat16(hp);     hp = fmaf(e1, hp, h1);
    hbuf[(s0 + 2 * DI_) * N_ + n] = __float2bfloat16(hp); hp = fmaf(e2, hp, h2);
    hbuf[(s0 + 3 * DI_) * N_ + n] = __float2bfloat16(hp); hp = fmaf(e3, hp, h3);
  }
}

// ---------------- G: scan phase 3 — replay with true init, emit y into ysum ----------------
__global__ __launch_bounds__(256, 4) void k_scan3(
    const float* __restrict__ xdbl, const float* __restrict__ xc,
    const float* __restrict__ dtw, const float* __restrict__ dtb,
    const float* __restrict__ alog, const float* __restrict__ Dsw,
    const bf16* __restrict__ hbuf, float* __restrict__ ysum) {
  int w = threadIdx.x >> 6, d = threadIdx.x & 63;
  int chunk = blockIdx.x * 4 + w, k = blockIdx.y, bb = blockIdx.z;
  float w0 = dtw[(k * DI_ + d) * 2 + 0], w1 = dtw[(k * DI_ + d) * 2 + 1];
  float bia = dtb[k * DI_ + d];
  float Dk = Dsw[k * DI_ + d];
  float A[N_], h[N_];
  size_t base = (size_t)((bb * K_ + k) * CH_ + chunk) * DI_ + d;
#pragma unroll
  for (int n = 0; n < N_; n++) {
    A[n] = -__expf(alog[(k * DI_ + d) * N_ + n]);
    h[n] = b2f(hbuf[base * N_ + n]);
  }
  int idx0, stride;
  chunk_addr(k, chunk, idx0, stride);
  const float* xdb = xdbl + (size_t)(bb * K_ + k) * L_ * 34;
  const float* xcb = xc + (size_t)bb * L_ * DI_;
  float* yb = ysum + (size_t)bb * L_ * DI_;
  int idx = idx0;
  float t0 = xdb[(size_t)idx * 34], t1 = xdb[(size_t)idx * 34 + 1];
  float u = xcb[(size_t)idx * DI_ + d];
  for (int s = 0; s < CL_; s++) {
    int nidx = (s + 1 < CL_) ? idx + stride : idx0;
    float nt0 = xdb[(size_t)nidx * 34], nt1 = xdb[(size_t)nidx * 34 + 1];
    float nu = xcb[(size_t)nidx * DI_ + d];
    const float* p = xdb + (size_t)idx * 34;
    float dt = softplusf(fmaf(t0, w0, fmaf(t1, w1, bia)));
    float du = dt * u;
    float y = 0.f;
#pragma unroll
    for (int n = 0; n < N_; n++) {
      h[n] = fmaf(__expf(dt * A[n]), h[n], du * p[2 + n]);
      y = fmaf(h[n], p[18 + n], y);
    }
    y = fmaf(Dk, u, y);
    atomicAdd(&yb[(size_t)idx * DI_ + d], y);
    idx = nidx; t0 = nt0; t1 = nt1; u = nu;
  }
}

// ---------------- H: LN(64)*silu(z), out_proj (64->32), residual -> xm ----------------
__global__ void k_combine(const float* __restrict__ ysum, const float* __restrict__ xzB,
                          const float* __restrict__ xd, const float* __restrict__ onw,
                          const float* __restrict__ onb, const float* __restrict__ outw,
                          const float* __restrict__ mssc, float* __restrict__ xm) {
  int w = threadIdx.x >> 6, d = threadIdx.x & 63;
  int idx = blockIdx.x * 4 + w, bb = blockIdx.y;
  int b = bb & 1, co = (bb >> 1) * HD_;
  float y = ysum[(size_t)(bb * L_ + idx) * DI_ + d];
  float s = y, sq = y * y;
#pragma unroll
  for (int m = 1; m < 64; m <<= 1) { s += __shfl_xor(s, m, 64); sq += __shfl_xor(sq, m, 64); }
  float mean = s * (1.f / DI_);
  float var = sq * (1.f / DI_) - mean * mean;
  float rstd = rsqrtf(var + EPSF);
  float yn = (y - mean) * rstd * onw[d] + onb[d];
  float z = xzB[(size_t)(bb * L_ + idx) * 64 + d];
  float g = yn * (z / (1.f + __expf(-z)));
  __shared__ float gs[4][DI_];
  gs[w][d] = g;
  __syncthreads();
  if (d < HD_) {
    float acc = 0.f;
#pragma unroll
    for (int dd = 0; dd < DI_; dd++) acc = fmaf(gs[w][dd], outw[dd * HD_ + d], acc);
    size_t xi = (size_t)(b * C_ + co + d) * L_ + idx;
    float xp = xd[xi];
    xm[xi] = mssc[0] * xp + xp + acc;
  }
}

// ---------------- I: fused instance-norm stats (xm) + global mean/max pool (x) ----------------
__global__ void k_stats(const float* __restrict__ xm, const float* __restrict__ x,
                        float* __restrict__ inm, float* __restrict__ inr,
                        float* __restrict__ xmean, float* __restrict__ xmax) {
  int bc = blockIdx.x, t = threadIdx.x;
  const float* pm = xm + (size_t)bc * L_;
  const float* px = x + (size_t)bc * L_;
  float s = 0.f, sq = 0.f, xs = 0.f, mx = -1e30f;
  for (int i = t; i < L_; i += 256) {
    float v = pm[i]; s += v; sq = fmaf(v, v, sq);
    float xv = px[i]; xs += xv; mx = fmaxf(mx, xv);
  }
  __shared__ float red[16];
#pragma unroll
  for (int m = 1; m < 64; m <<= 1) {
    s += __shfl_xor(s, m, 64); sq += __shfl_xor(sq, m, 64);
    xs += __shfl_xor(xs, m, 64); mx = fmaxf(mx, __shfl_xor(mx, m, 64));
  }
  int wid = t >> 6;
  if ((t & 63) == 0) { red[wid] = s; red[4 + wid] = sq; red[8 + wid] = xs; red[12 + wid] = mx; }
  __syncthreads();
  if (t == 0) {
    s = red[0] + red[1] + red[2] + red[3];
    sq = red[4] + red[5] + red[6] + red[7];
    xs = red[8] + red[9] + red[10] + red[11];
    mx = fmaxf(fmaxf(red[12], red[13]), fmaxf(red[14], red[15]));
    float mean = s * (1.f / L_);
    float var = sq * (1.f / L_) - mean * mean;
    inm[bc] = mean;
    inr[bc] = rsqrtf(var + EPSF);
    xmean[bc] = xs * (1.f / L_);
    xmax[bc] = mx;
  }
}

// ---------------- L: IN apply + leaky_relu + sigmoid-gate*x -> xs2 ----------------
__global__ void k_xs(const float* __restrict__ xm, const float* __restrict__ inm,
                     const float* __restrict__ inr, const float* __restrict__ msw,
                     const float* __restrict__ msb, const float* __restrict__ xmean,
                     const float* __restrict__ xmax, const float* __restrict__ maw,
                     const float* __restrict__ mab, const float* __restrict__ x,
                     float* __restrict__ xs2) {
  int t = blockIdx.x * 256 + threadIdx.x;
  int bc = t / L_, c = bc & 63, b = bc >> 6;   // uniform per block (256 | L)
  __shared__ float gsh;
  if (threadIdx.x < 64) {
    int ic = threadIdx.x;
    float p = xmean[b * 64 + ic] * maw[(c * 128 + ic) * 9 + 4]
            + xmax[b * 64 + ic] * maw[(c * 128 + 64 + ic) * 9 + 4];
#pragma unroll
    for (int m = 1; m < 64; m <<= 1) p += __shfl_xor(p, m, 64);
    if (ic == 0) gsh = 1.f / (1.f + __expf(-(p + mab[c])));
  }
  __syncthreads();
  float gate = gsh;
  float v = xm[t];
  v = (v - inm[bc]) * inr[bc] * msw[c] + msb[c];
  v = v > 0.f ? v : 0.01f * v;
  xs2[t] = v + gate * x[t];
}

// ---------------- M: axial dw convs + BN + relu -> skip (straight to d_out) ----------------
__global__ void k_axbn(const float* __restrict__ xs2, const float* __restrict__ hw,
                       const float* __restrict__ hb, const float* __restrict__ wwt,
                       const float* __restrict__ wb, const float* __restrict__ bnw,
                       const float* __restrict__ bnb, const float* __restrict__ bnm,
                       const float* __restrict__ bnv, float* __restrict__ skipo) {
  int t = blockIdx.x * 256 + threadIdx.x;
  if (t >= B_ * C_ * L_) return;
  int wi = t % W_, hi = (t / W_) % H_, c = (t / L_) % C_;
  float a = xs2[t];
  float hacc = hb[c];
#pragma unroll
  for (int dy = -1; dy <= 1; dy++) {
    int hh = hi + dy; if (hh < 0 || hh >= H_) continue;
    hacc = fmaf(xs2[t + dy * W_], hw[c * 3 + dy + 1], hacc);
  }
  float wacc = wb[c];
#pragma unroll
  for (int dx = -1; dx <= 1; dx++) {
    int ww = wi + dx; if (ww < 0 || ww >= W_) continue;
    wacc = fmaf(xs2[t + dx], wwt[c * 3 + dx + 1], wacc);
  }
  float v = a + hacc + wacc;
  float sv = (v - bnm[c]) * rsqrtf(bnv[c] + EPSF) * bnw[c] + bnb[c];
  skipo[t] = fmaxf(sv, 0.f);
}

// ---------------- N: 1x1 conv (64->128) + 2x2 maxpool -> down ----------------
__global__ void k_pwpool(const float* __restrict__ skipo, const float* __restrict__ pww,
                         const float* __restrict__ pwb, float* __restrict__ down) {
  int h2 = blockIdx.x, b = blockIdx.y, t = threadIdx.x;
  __shared__ float sk[64 * 192];  // [c][r(2)][w(96)]
  for (int i = t; i < 64 * 192; i += 256) {
    int c = i / 192, rw = i % 192, r = rw / 96, wcol = rw % 96;
    sk[i] = skipo[((size_t)(b * C_ + c) * H_ + (2 * h2 + r)) * W_ + wcol];
  }
  __syncthreads();
  for (int o = t; o < OC_ * 48; o += 256) {
    int oc = o / 48, w2 = o % 48;
    float s0 = 0.f, s1 = 0.f, s2 = 0.f, s3 = 0.f;
#pragma unroll 8
    for (int c = 0; c < 64; c++) {
      float wv = pww[oc * 64 + c];
      const float* sp = &sk[c * 192 + 2 * w2];
      s0 = fmaf(sp[0], wv, s0);
      s1 = fmaf(sp[1], wv, s1);
      s2 = fmaf(sp[96], wv, s2);
      s3 = fmaf(sp[97], wv, s3);
    }
    float v = fmaxf(fmaxf(s0, s1), fmaxf(s2, s3)) + pwb[oc];
    down[((size_t)(b * OC_ + oc) * 48 + h2) * 48 + w2] = v;
  }
}

extern "C" void kernel_launch(void* const* d_in, const int* in_sizes, int n_in,
                              void* d_out, int out_size, void* d_ws, size_t ws_size,
                              hipStream_t stream) {
  const float* x     = (const float*)d_in[0];
  const float* dw33w = (const float*)d_in[1];
  const float* dw33b = (const float*)d_in[2];
  const float* msw   = (const float*)d_in[3];
  const float* msb   = (const float*)d_in[4];
  const float* mssc  = (const float*)d_in[5];
  const float* lnw   = (const float*)d_in[6];
  const float* lnb   = (const float*)d_in[7];
  const float* inw   = (const float*)d_in[8];
  const float* cw    = (const float*)d_in[9];
  const float* cb    = (const float*)d_in[10];
  const float* xpw   = (const float*)d_in[11];
  const float* dtw   = (const float*)d_in[12];
  const float* dtb   = (const float*)d_in[13];
  const float* alog  = (const float*)d_in[14];
  const float* Dsw   = (const float*)d_in[15];
  const float* onw   = (const float*)d_in[16];
  const float* onb   = (const float*)d_in[17];
  const float* outw  = (const float*)d_in[18];
  const float* maw   = (const float*)d_in[19];
  const float* mab   = (const float*)d_in[20];
  const float* ahw   = (const float*)d_in[21];
  const float* ahb   = (const float*)d_in[22];
  const float* aww   = (const float*)d_in[23];
  const float* awb   = (const float*)d_in[24];
  const float* pww   = (const float*)d_in[25];
  const float* pwb   = (const float*)d_in[26];
  const float* bnw   = (const float*)d_in[27];
  const float* bnb   = (const float*)d_in[28];
  const float* bnm   = (const float*)d_in[29];
  const float* bnv   = (const float*)d_in[30];

  float* ws = (float*)d_ws;
  float* xd   = ws;                     // 1,179,648
  float* xzA  = xd + 1179648;           // 2,359,296 (dead after k_dwsilu)
  bf16*  hbuf = (bf16*)xzA;             // 6,291,456 bf16 -> 3,145,728 slots
  float* xzB  = xzA + 3145728;          // 2,359,296
  float* xc   = xzB + 2359296;          // 2,359,296
  float* xdbl = xc + 2359296;           // 5,013,504
  float* ssum = xdbl + 5013504;         // 393,216
  float* ysum = ssum + 393216;          // 2,359,296
  float* xm   = ysum + 2359296;         // 1,179,648
  float* xs2  = xm + 1179648;           // 1,179,648
  bf16*  xch  = (bf16*)xs2;             // overlays xs2 (dead until k_xs)
  float* st   = xs2 + 1179648;          // 512
  float* inm = st, *inr = st + 128, *xmean = st + 256, *xmaxv = st + 384;
  bf16*  wh   = (bf16*)(st + 512);      // 9,216 bf16 = 4,608 float slots

  float* outp = (float*)d_out;
  float* down = outp;
  float* skipo = outp + DOWN_SZ;

  dim3 b256(256);
  int nEl = B_ * C_ * L_;

  k_wprep<<<dim3(36), b256, 0, stream>>>(xpw, wh);
  k_dw33<<<dim3((nEl + 255) / 256), b256, 0, stream>>>(x, dw33w, dw33b, xd);
  k_ln_inproj<<<dim3(L_ / 64, BB_), b256, 0, stream>>>(xd, lnw, lnb, inw, xzA, xzB);
  k_dwsilu<<<dim3(BB_ * L_ * DI_ / 256), b256, 0, stream>>>(xzA, cw, cb, xc, xch);
  k_xdbl_mfma<<<dim3(L_ / 64, BB_), b256, 0, stream>>>(xch, wh, xdbl);
  k_scan1<<<dim3(CH_ / 4, K_, BB_), b256, 0, stream>>>(xdbl, xc, dtw, dtb, alog, hbuf, ssum, ysum);
  k_scan2<<<dim3(BB_ * K_ * DI_ * N_ / 256), b256, 0, stream>>>(alog, ssum, hbuf);
  k_scan3<<<dim3(CH_ / 4, K_, BB_), b256, 0, stream>>>(xdbl, xc, dtw, dtb, alog, Dsw, hbuf, ysum);
  k_combine<<<dim3(L_ / 4, BB_), b256, 0, stream>>>(ysum, xzB, xd, onw, onb, outw, mssc, xm);
  k_stats<<<dim3(B_ * C_), b256, 0, stream>>>(xm, x, inm, inr, xmean, xmaxv);
  k_xs<<<dim3((nEl + 255) / 256), b256, 0, stream>>>(xm, inm, inr, msw, msb, xmean, xmaxv, maw, mab, x, xs2);
  k_axbn<<<dim3((nEl + 255) / 256), b256, 0, stream>>>(xs2, ahw, ahb, aww, awb, bnw, bnb, bnm, bnv, skipo);
  k_pwpool<<<dim3(48, B_), b256, 0, stream>>>(skipo, pww, pwb, down);
}

// Round 5
// 373.206 us; speedup vs baseline: 1.2896x; 1.0276x over previous
//
#include <hip/hip_runtime.h>
#include <hip/hip_bf16.h>

typedef __hip_bfloat16 bf16;
#define DEV __device__ __forceinline__

constexpr int B_ = 2, C_ = 64, H_ = 96, W_ = 96, L_ = 9216;
constexpr int HD_ = 32, DI_ = 64, N_ = 16, K_ = 4, BB_ = 4;
constexpr int OC_ = 128;
constexpr int CH_ = 384, CL_ = 24;          // scan chunking: 384 chunks of 24 steps
constexpr float EPSF = 1e-5f;
constexpr int DOWN_SZ = B_ * OC_ * 48 * 48; // 589824

typedef __attribute__((ext_vector_type(8))) short short8;   // 8 bf16 (4 VGPRs)
typedef __attribute__((ext_vector_type(4))) float f32x4;    // MFMA accumulator

DEV float softplusf(float x) { return x > 15.f ? x : __logf(1.f + __expf(x)); }
DEV float b2f(bf16 v) { return __bfloat162float(v); }

// log(1..16): used to detect A[n] = (n+1)*A[0] structure (VMamba default A_logs)
__constant__ float kLogN[16] = {
  0.0f, 0.69314718f, 1.09861229f, 1.38629436f, 1.60943791f, 1.79175947f,
  1.94591015f, 2.07944154f, 2.19722458f, 2.30258509f, 2.39789527f,
  2.48490665f, 2.56494936f, 2.63905733f, 2.70805020f, 2.77258872f};

// per-chunk scan addressing: spatial idx = idx0 + s*stride, s in [0,CL)
DEV void chunk_addr(int k, int chunk, int& idx0, int& stride) {
  int r4 = chunk & 3, q = chunk >> 2;
  if (k == 0)      { idx0 = chunk * CL_;                        stride = 1;   }
  else if (k == 1) { idx0 = (24 * r4) * 96 + q;                 stride = 96;  }
  else if (k == 2) { idx0 = L_ - 1 - chunk * CL_;               stride = -1;  }
  else             { idx0 = (95 - 24 * r4) * 96 + (95 - q);     stride = -96; }
}

// ---------------- A: depthwise 3x3 (x -> xd, f32) ----------------
__global__ void k_dw33(const float* __restrict__ x, const float* __restrict__ w,
                       const float* __restrict__ bias, float* __restrict__ out) {
  int t = blockIdx.x * 256 + threadIdx.x;
  if (t >= B_ * C_ * L_) return;
  int wi = t % W_, hi = (t / W_) % H_, c = (t / L_) % C_;
  float acc = bias[c];
#pragma unroll
  for (int dy = -1; dy <= 1; dy++) {
    int hh = hi + dy; if (hh < 0 || hh >= H_) continue;
#pragma unroll
    for (int dx = -1; dx <= 1; dx++) {
      int ww = wi + dx; if (ww < 0 || ww >= W_) continue;
      acc = fmaf(x[t + dy * W_ + dx], w[c * 9 + (dy + 1) * 3 + (dx + 1)], acc);
    }
  }
  out[t] = acc;
}

// ---------------- B: LayerNorm(32) + in_proj (32->128), 64-idx tile GEMM ----------------
__global__ __launch_bounds__(256, 4) void k_ln_inproj(
    const float* __restrict__ xd, const float* __restrict__ lnw,
    const float* __restrict__ lnb, const float* __restrict__ inw,
    float* __restrict__ xzA, float* __restrict__ xzB) {
  int bb = blockIdx.y, t = threadIdx.x;
  int b = bb & 1, co = (bb >> 1) * HD_;
  int idx0 = blockIdx.x * 64;
  __shared__ float xds[32 * 68];
  __shared__ float meanA[64], rstdA[64];
  int lane = t & 63;
  for (int r = 0; r < 8; r++) {
    int c = r * 4 + (t >> 6);
    xds[c * 68 + lane] = xd[(size_t)(b * C_ + co + c) * L_ + idx0 + lane];
  }
  __syncthreads();
  if (t < 64) {
    float s = 0.f, sq = 0.f;
#pragma unroll
    for (int c = 0; c < 32; c++) { float v = xds[c * 68 + t]; s += v; sq = fmaf(v, v, sq); }
    float mean = s * (1.f / HD_);
    float var = sq * (1.f / HD_) - mean * mean;
    meanA[t] = mean; rstdA[t] = rsqrtf(var + EPSF);
  }
  __syncthreads();
  for (int i = t; i < 2048; i += 256) {
    int c = i >> 6, idx = i & 63;
    float v = xds[c * 68 + idx];
    xds[c * 68 + idx] = (v - meanA[idx]) * rstdA[idx] * lnw[c] + lnb[c];
  }
  __syncthreads();
  int oc = t & 127, g = t >> 7;
  float acc[32];
#pragma unroll
  for (int j = 0; j < 32; j++) acc[j] = 0.f;
  for (int c = 0; c < 32; c++) {
    float wv = inw[c * 128 + oc];
    const float4* row = reinterpret_cast<const float4*>(&xds[c * 68 + g * 32]);
#pragma unroll
    for (int j4 = 0; j4 < 8; j4++) {
      float4 xv = row[j4];
      acc[j4 * 4 + 0] = fmaf(xv.x, wv, acc[j4 * 4 + 0]);
      acc[j4 * 4 + 1] = fmaf(xv.y, wv, acc[j4 * 4 + 1]);
      acc[j4 * 4 + 2] = fmaf(xv.z, wv, acc[j4 * 4 + 2]);
      acc[j4 * 4 + 3] = fmaf(xv.w, wv, acc[j4 * 4 + 3]);
    }
  }
  float* dst = (oc < 64) ? xzA : xzB;
  int occ = oc & 63;
#pragma unroll
  for (int j = 0; j < 32; j++) {
    int idx = g * 32 + j;
    dst[(size_t)(bb * L_ + idx0 + idx) * 64 + occ] = acc[j];
  }
}

// ---------------- C: depthwise 3x3 + SiLU -> xch (bf16, [bb,l,d]) ----------------
__global__ void k_dwsilu(const float* __restrict__ xzA, const float* __restrict__ cw,
                         const float* __restrict__ cb, bf16* __restrict__ xch) {
  int t = blockIdx.x * 256 + threadIdx.x;
  int d = t & 63, idx = (t >> 6) % L_, bb = t / (L_ * DI_);
  int wi = idx % W_, hi = idx / W_;
  float acc = cb[d];
#pragma unroll
  for (int dy = -1; dy <= 1; dy++) {
    int hh = hi + dy; if (hh < 0 || hh >= H_) continue;
#pragma unroll
    for (int dx = -1; dx <= 1; dx++) {
      int ww = wi + dx; if (ww < 0 || ww >= W_) continue;
      acc = fmaf(xzA[(size_t)(bb * L_ + hh * W_ + ww) * 64 + d],
                 cw[d * 9 + (dy + 1) * 3 + (dx + 1)], acc);
    }
  }
  acc = acc / (1.f + __expf(-acc));
  xch[t] = __float2bfloat16(acc);
}

// ---------------- D0: weight prep — 136x64 f32 -> 144x64 bf16 (zero-padded) ----------------
__global__ void k_wprep(const float* __restrict__ xpw, bf16* __restrict__ wh) {
  int i = blockIdx.x * 256 + threadIdx.x;  // 144*64
  if (i >= 144 * 64) return;
  int n = i >> 6;
  wh[i] = __float2bfloat16(n < 136 ? xpw[i] : 0.f);
}

// ---------------- D: x_dbl projection via MFMA: [36864 x 64] @ [64 x 136] ----------------
__global__ __launch_bounds__(256, 4) void k_xdbl_mfma(
    const bf16* __restrict__ xch, const bf16* __restrict__ wh,
    float* __restrict__ xdbl) {
  int w = threadIdx.x >> 6, lane = threadIdx.x & 63;
  int bb = blockIdx.y;
  int mtile = blockIdx.x * 4 + w;
  int idx0 = mtile * 16;
  int m = lane & 15, quad = lane >> 4;
  const bf16* arow = xch + ((size_t)bb * L_ + idx0 + m) * 64 + quad * 8;
  short8 a0 = *reinterpret_cast<const short8*>(arow);
  short8 a1 = *reinterpret_cast<const short8*>(arow + 32);
#pragma unroll
  for (int nt = 0; nt < 9; nt++) {
    int n = nt * 16 + m;
    const bf16* brow = wh + n * 64 + quad * 8;
    short8 b0 = *reinterpret_cast<const short8*>(brow);
    short8 b1 = *reinterpret_cast<const short8*>(brow + 32);
    f32x4 acc = {0.f, 0.f, 0.f, 0.f};
    acc = __builtin_amdgcn_mfma_f32_16x16x32_bf16(a0, b0, acc, 0, 0, 0);
    acc = __builtin_amdgcn_mfma_f32_16x16x32_bf16(a1, b1, acc, 0, 0, 0);
    if (n < 136) {
      int k4 = (n >= 102) ? 3 : (n >= 68) ? 2 : (n >= 34) ? 1 : 0;
      int c = n - k4 * 34;
      float* dst = xdbl + ((size_t)(bb * K_ + k4) * L_ + idx0 + quad * 4) * 34 + c;
      dst[0] = acc[0]; dst[34] = acc[1]; dst[68] = acc[2]; dst[102] = acc[3];
    }
  }
}

// ---------------- E: scan phase 1 — per-chunk local state (h0=0) + sum(dt) ----------------
__global__ __launch_bounds__(256, 4) void k_scan1(
    const float* __restrict__ xdbl, const bf16* __restrict__ xch,
    const float* __restrict__ dtw, const float* __restrict__ dtb,
    const float* __restrict__ alog, bf16* __restrict__ hbuf,
    float* __restrict__ ssum, float* __restrict__ ysum) {
  int w = threadIdx.x >> 6, d = threadIdx.x & 63;
  int chunk = blockIdx.x * 4 + w, k = blockIdx.y, bb = blockIdx.z;
  if (k == 0) {  // zero ysum slice before scan3's atomics
    float* yb = ysum + ((size_t)bb * L_ + chunk * CL_) * DI_ + d;
#pragma unroll
    for (int j = 0; j < CL_; j++) yb[j * DI_] = 0.f;
  }
  float w0 = dtw[(k * DI_ + d) * 2 + 0], w1 = dtw[(k * DI_ + d) * 2 + 1];
  float bia = dtb[k * DI_ + d];
  const float* al = alog + (k * DI_ + d) * N_;
  float a0 = al[0];
  bool lin = true;
#pragma unroll
  for (int n = 1; n < N_; n++) lin = lin && (fabsf(al[n] - a0 - kLogN[n]) < 3e-5f);
  bool chain = (__ballot(lin) == ~0ull);
  float A1 = -__expf(a0);
  float h[N_];
#pragma unroll
  for (int n = 0; n < N_; n++) h[n] = 0.f;
  int idx0, stride;
  chunk_addr(k, chunk, idx0, stride);
  const float* xdb = xdbl + (size_t)(bb * K_ + k) * L_ * 34;
  const bf16* xcb = xch + (size_t)bb * L_ * DI_;
  float S = 0.f;
  int idx = idx0;
  float t0 = xdb[(size_t)idx * 34], t1 = xdb[(size_t)idx * 34 + 1];
  float u = b2f(xcb[(size_t)idx * DI_ + d]);
  if (chain) {
    for (int s = 0; s < CL_; s++) {
      int nidx = (s + 1 < CL_) ? idx + stride : idx0;
      float nt0 = xdb[(size_t)nidx * 34], nt1 = xdb[(size_t)nidx * 34 + 1];
      float nu = b2f(xcb[(size_t)nidx * DI_ + d]);
      const float* p = xdb + (size_t)idx * 34;
      float dt = softplusf(fmaf(t0, w0, fmaf(t1, w1, bia)));
      S += dt;
      float du = dt * u;
      float e1 = __expf(dt * A1), ep = e1;
      h[0] = fmaf(e1, h[0], du * p[2]);
#pragma unroll
      for (int n = 1; n < N_; n++) { ep *= e1; h[n] = fmaf(ep, h[n], du * p[2 + n]); }
      idx = nidx; t0 = nt0; t1 = nt1; u = nu;
    }
  } else {
    float A[N_];
#pragma unroll
    for (int n = 0; n < N_; n++) A[n] = -__expf(al[n]);
    for (int s = 0; s < CL_; s++) {
      int nidx = (s + 1 < CL_) ? idx + stride : idx0;
      float nt0 = xdb[(size_t)nidx * 34], nt1 = xdb[(size_t)nidx * 34 + 1];
      float nu = b2f(xcb[(size_t)nidx * DI_ + d]);
      const float* p = xdb + (size_t)idx * 34;
      float dt = softplusf(fmaf(t0, w0, fmaf(t1, w1, bia)));
      S += dt;
      float du = dt * u;
#pragma unroll
      for (int n = 0; n < N_; n++)
        h[n] = fmaf(__expf(dt * A[n]), h[n], du * p[2 + n]);
      idx = nidx; t0 = nt0; t1 = nt1; u = nu;
    }
  }
  size_t base = (size_t)((bb * K_ + k) * CH_ + chunk) * DI_ + d;
  ssum[base] = S;
#pragma unroll
  for (int n = 0; n < N_; n++) hbuf[base * N_ + n] = __float2bfloat16(h[n]);
}

// ---------------- F: scan phase 2 — exclusive scan over chunk summaries (pipelined) ----------------
__global__ void k_scan2(const float* __restrict__ alog, const float* __restrict__ ssum,
                        bf16* __restrict__ hbuf) {
  int t = blockIdx.x * 256 + threadIdx.x;
  int n = t & 15, d = (t >> 4) & 63, kk = (t >> 10) & 3, bb = t >> 12;
  float A = -__expf(alog[(kk * DI_ + d) * N_ + n]);
  size_t row = (size_t)(bb * K_ + kk) * CH_ * DI_ + d;
  constexpr int U = 16;
  float Sb[U], hb[U];
#pragma unroll
  for (int j = 0; j < U; j++) {
    size_t sb = row + (size_t)j * DI_;
    Sb[j] = ssum[sb]; hb[j] = b2f(hbuf[sb * N_ + n]);
  }
  float hp = 0.f;
  for (int c = 0; c < CH_; c += U) {
    float S2[U], h2[U];
    if (c + U < CH_) {
#pragma unroll
      for (int j = 0; j < U; j++) {
        size_t sb = row + (size_t)(c + U + j) * DI_;
        S2[j] = ssum[sb]; h2[j] = b2f(hbuf[sb * N_ + n]);
      }
    } else {
#pragma unroll
      for (int j = 0; j < U; j++) { S2[j] = 0.f; h2[j] = 0.f; }
    }
#pragma unroll
    for (int j = 0; j < U; j++) {
      size_t sb = row + (size_t)(c + j) * DI_;
      float e = __expf(A * Sb[j]);
      hbuf[sb * N_ + n] = __float2bfloat16(hp);
      hp = fmaf(e, hp, hb[j]);
    }
#pragma unroll
    for (int j = 0; j < U; j++) { Sb[j] = S2[j]; hb[j] = h2[j]; }
  }
}

// ---------------- G: scan phase 3 — replay with true init, emit y into ysum ----------------
__global__ __launch_bounds__(256, 4) void k_scan3(
    const float* __restrict__ xdbl, const bf16* __restrict__ xch,
    const float* __restrict__ dtw, const float* __restrict__ dtb,
    const float* __restrict__ alog, const float* __restrict__ Dsw,
    const bf16* __restrict__ hbuf, float* __restrict__ ysum) {
  int w = threadIdx.x >> 6, d = threadIdx.x & 63;
  int chunk = blockIdx.x * 4 + w, k = blockIdx.y, bb = blockIdx.z;
  float w0 = dtw[(k * DI_ + d) * 2 + 0], w1 = dtw[(k * DI_ + d) * 2 + 1];
  float bia = dtb[k * DI_ + d];
  float Dk = Dsw[k * DI_ + d];
  const float* al = alog + (k * DI_ + d) * N_;
  float a0 = al[0];
  bool lin = true;
#pragma unroll
  for (int n = 1; n < N_; n++) lin = lin && (fabsf(al[n] - a0 - kLogN[n]) < 3e-5f);
  bool chain = (__ballot(lin) == ~0ull);
  float A1 = -__expf(a0);
  float h[N_];
  size_t base = (size_t)((bb * K_ + k) * CH_ + chunk) * DI_ + d;
#pragma unroll
  for (int n = 0; n < N_; n++) h[n] = b2f(hbuf[base * N_ + n]);
  int idx0, stride;
  chunk_addr(k, chunk, idx0, stride);
  const float* xdb = xdbl + (size_t)(bb * K_ + k) * L_ * 34;
  const bf16* xcb = xch + (size_t)bb * L_ * DI_;
  float* yb = ysum + (size_t)bb * L_ * DI_;
  int idx = idx0;
  float t0 = xdb[(size_t)idx * 34], t1 = xdb[(size_t)idx * 34 + 1];
  float u = b2f(xcb[(size_t)idx * DI_ + d]);
  if (chain) {
    for (int s = 0; s < CL_; s++) {
      int nidx = (s + 1 < CL_) ? idx + stride : idx0;
      float nt0 = xdb[(size_t)nidx * 34], nt1 = xdb[(size_t)nidx * 34 + 1];
      float nu = b2f(xcb[(size_t)nidx * DI_ + d]);
      const float* p = xdb + (size_t)idx * 34;
      float dt = softplusf(fmaf(t0, w0, fmaf(t1, w1, bia)));
      float du = dt * u;
      float e1 = __expf(dt * A1), ep = e1;
      h[0] = fmaf(e1, h[0], du * p[2]);
      float y = h[0] * p[18];
#pragma unroll
      for (int n = 1; n < N_; n++) {
        ep *= e1;
        h[n] = fmaf(ep, h[n], du * p[2 + n]);
        y = fmaf(h[n], p[18 + n], y);
      }
      y = fmaf(Dk, u, y);
      atomicAdd(&yb[(size_t)idx * DI_ + d], y);
      idx = nidx; t0 = nt0; t1 = nt1; u = nu;
    }
  } else {
    float A[N_];
#pragma unroll
    for (int n = 0; n < N_; n++) A[n] = -__expf(al[n]);
    for (int s = 0; s < CL_; s++) {
      int nidx = (s + 1 < CL_) ? idx + stride : idx0;
      float nt0 = xdb[(size_t)nidx * 34], nt1 = xdb[(size_t)nidx * 34 + 1];
      float nu = b2f(xcb[(size_t)nidx * DI_ + d]);
      const float* p = xdb + (size_t)idx * 34;
      float dt = softplusf(fmaf(t0, w0, fmaf(t1, w1, bia)));
      float du = dt * u;
      float y = 0.f;
#pragma unroll
      for (int n = 0; n < N_; n++) {
        h[n] = fmaf(__expf(dt * A[n]), h[n], du * p[2 + n]);
        y = fmaf(h[n], p[18 + n], y);
      }
      y = fmaf(Dk, u, y);
      atomicAdd(&yb[(size_t)idx * DI_ + d], y);
      idx = nidx; t0 = nt0; t1 = nt1; u = nu;
    }
  }
}

// ---------------- H: LN(64)*silu(z), out_proj (64->32), residual -> xm ----------------
__global__ void k_combine(const float* __restrict__ ysum, const float* __restrict__ xzB,
                          const float* __restrict__ xd, const float* __restrict__ onw,
                          const float* __restrict__ onb, const float* __restrict__ outw,
                          const float* __restrict__ mssc, float* __restrict__ xm) {
  int w = threadIdx.x >> 6, d = threadIdx.x & 63;
  int idx = blockIdx.x * 4 + w, bb = blockIdx.y;
  int b = bb & 1, co = (bb >> 1) * HD_;
  float y = ysum[(size_t)(bb * L_ + idx) * DI_ + d];
  float s = y, sq = y * y;
#pragma unroll
  for (int m = 1; m < 64; m <<= 1) { s += __shfl_xor(s, m, 64); sq += __shfl_xor(sq, m, 64); }
  float mean = s * (1.f / DI_);
  float var = sq * (1.f / DI_) - mean * mean;
  float rstd = rsqrtf(var + EPSF);
  float yn = (y - mean) * rstd * onw[d] + onb[d];
  float z = xzB[(size_t)(bb * L_ + idx) * 64 + d];
  float g = yn * (z / (1.f + __expf(-z)));
  __shared__ float gs[4][DI_];
  gs[w][d] = g;
  __syncthreads();
  if (d < HD_) {
    float acc = 0.f;
#pragma unroll
    for (int dd = 0; dd < DI_; dd++) acc = fmaf(gs[w][dd], outw[dd * HD_ + d], acc);
    size_t xi = (size_t)(b * C_ + co + d) * L_ + idx;
    float xp = xd[xi];
    xm[xi] = mssc[0] * xp + xp + acc;
  }
}

// ---------------- I: fused instance-norm stats (xm) + global mean/max pool (x) ----------------
__global__ __launch_bounds__(1024) void k_stats(
    const float* __restrict__ xm, const float* __restrict__ x,
    float* __restrict__ inm, float* __restrict__ inr,
    float* __restrict__ xmean, float* __restrict__ xmax) {
  int bc = blockIdx.x, t = threadIdx.x;
  const float* pm = xm + (size_t)bc * L_;
  const float* px = x + (size_t)bc * L_;
  float s = 0.f, sq = 0.f, xs = 0.f, mx = -1e30f;
  for (int i = t; i < L_; i += 1024) {
    float v = pm[i]; s += v; sq = fmaf(v, v, sq);
    float xv = px[i]; xs += xv; mx = fmaxf(mx, xv);
  }
  __shared__ float red[64];
#pragma unroll
  for (int m = 1; m < 64; m <<= 1) {
    s += __shfl_xor(s, m, 64); sq += __shfl_xor(sq, m, 64);
    xs += __shfl_xor(xs, m, 64); mx = fmaxf(mx, __shfl_xor(mx, m, 64));
  }
  int wid = t >> 6;
  if ((t & 63) == 0) { red[wid] = s; red[16 + wid] = sq; red[32 + wid] = xs; red[48 + wid] = mx; }
  __syncthreads();
  if (t == 0) {
    s = 0.f; sq = 0.f; xs = 0.f; mx = -1e30f;
#pragma unroll
    for (int i = 0; i < 16; i++) {
      s += red[i]; sq += red[16 + i]; xs += red[32 + i]; mx = fmaxf(mx, red[48 + i]);
    }
    float mean = s * (1.f / L_);
    float var = sq * (1.f / L_) - mean * mean;
    inm[bc] = mean;
    inr[bc] = rsqrtf(var + EPSF);
    xmean[bc] = xs * (1.f / L_);
    xmax[bc] = mx;
  }
}

// ---------------- L: IN apply + leaky_relu + sigmoid-gate*x -> xs2 ----------------
__global__ void k_xs(const float* __restrict__ xm, const float* __restrict__ inm,
                     const float* __restrict__ inr, const float* __restrict__ msw,
                     const float* __restrict__ msb, const float* __restrict__ xmean,
                     const float* __restrict__ xmax, const float* __restrict__ maw,
                     const float* __restrict__ mab, const float* __restrict__ x,
                     float* __restrict__ xs2) {
  int t = blockIdx.x * 256 + threadIdx.x;
  int bc = t / L_, c = bc & 63, b = bc >> 6;   // uniform per block (256 | L)
  __shared__ float gsh;
  if (threadIdx.x < 64) {
    int ic = threadIdx.x;
    float p = xmean[b * 64 + ic] * maw[(c * 128 + ic) * 9 + 4]
            + xmax[b * 64 + ic] * maw[(c * 128 + 64 + ic) * 9 + 4];
#pragma unroll
    for (int m = 1; m < 64; m <<= 1) p += __shfl_xor(p, m, 64);
    if (ic == 0) gsh = 1.f / (1.f + __expf(-(p + mab[c])));
  }
  __syncthreads();
  float gate = gsh;
  float v = xm[t];
  v = (v - inm[bc]) * inr[bc] * msw[c] + msb[c];
  v = v > 0.f ? v : 0.01f * v;
  xs2[t] = v + gate * x[t];
}

// ---------------- M: axial dw convs + BN + relu -> skip (straight to d_out) ----------------
__global__ void k_axbn(const float* __restrict__ xs2, const float* __restrict__ hw,
                       const float* __restrict__ hb, const float* __restrict__ wwt,
                       const float* __restrict__ wb, const float* __restrict__ bnw,
                       const float* __restrict__ bnb, const float* __restrict__ bnm,
                       const float* __restrict__ bnv, float* __restrict__ skipo) {
  int t = blockIdx.x * 256 + threadIdx.x;
  if (t >= B_ * C_ * L_) return;
  int wi = t % W_, hi = (t / W_) % H_, c = (t / L_) % C_;
  float a = xs2[t];
  float hacc = hb[c];
#pragma unroll
  for (int dy = -1; dy <= 1; dy++) {
    int hh = hi + dy; if (hh < 0 || hh >= H_) continue;
    hacc = fmaf(xs2[t + dy * W_], hw[c * 3 + dy + 1], hacc);
  }
  float wacc = wb[c];
#pragma unroll
  for (int dx = -1; dx <= 1; dx++) {
    int ww = wi + dx; if (ww < 0 || ww >= W_) continue;
    wacc = fmaf(xs2[t + dx], wwt[c * 3 + dx + 1], wacc);
  }
  float v = a + hacc + wacc;
  float sv = (v - bnm[c]) * rsqrtf(bnv[c] + EPSF) * bnw[c] + bnb[c];
  skipo[t] = fmaxf(sv, 0.f);
}

// ---------------- N: 1x1 conv (64->128) + 2x2 maxpool -> down (oc split over z) ----------------
__global__ void k_pwpool(const float* __restrict__ skipo, const float* __restrict__ pww,
                         const float* __restrict__ pwb, float* __restrict__ down) {
  int h2 = blockIdx.x, b = blockIdx.y, t = threadIdx.x;
  int oc0 = blockIdx.z * 32;
  __shared__ float sk[64 * 192];  // [c][r(2)][w(96)]
  for (int i = t; i < 64 * 192; i += 256) {
    int c = i / 192, rw = i % 192, r = rw / 96, wcol = rw % 96;
    sk[i] = skipo[((size_t)(b * C_ + c) * H_ + (2 * h2 + r)) * W_ + wcol];
  }
  __syncthreads();
  for (int o = t; o < 32 * 48; o += 256) {
    int oc = oc0 + o / 48, w2 = o % 48;
    float s0 = 0.f, s1 = 0.f, s2 = 0.f, s3 = 0.f;
#pragma unroll 8
    for (int c = 0; c < 64; c++) {
      float wv = pww[oc * 64 + c];
      const float* sp = &sk[c * 192 + 2 * w2];
      s0 = fmaf(sp[0], wv, s0);
      s1 = fmaf(sp[1], wv, s1);
      s2 = fmaf(sp[96], wv, s2);
      s3 = fmaf(sp[97], wv, s3);
    }
    float v = fmaxf(fmaxf(s0, s1), fmaxf(s2, s3)) + pwb[oc];
    down[((size_t)(b * OC_ + oc) * 48 + h2) * 48 + w2] = v;
  }
}

extern "C" void kernel_launch(void* const* d_in, const int* in_sizes, int n_in,
                              void* d_out, int out_size, void* d_ws, size_t ws_size,
                              hipStream_t stream) {
  const float* x     = (const float*)d_in[0];
  const float* dw33w = (const float*)d_in[1];
  const float* dw33b = (const float*)d_in[2];
  const float* msw   = (const float*)d_in[3];
  const float* msb   = (const float*)d_in[4];
  const float* mssc  = (const float*)d_in[5];
  const float* lnw   = (const float*)d_in[6];
  const float* lnb   = (const float*)d_in[7];
  const float* inw   = (const float*)d_in[8];
  const float* cw    = (const float*)d_in[9];
  const float* cb    = (const float*)d_in[10];
  const float* xpw   = (const float*)d_in[11];
  const float* dtw   = (const float*)d_in[12];
  const float* dtb   = (const float*)d_in[13];
  const float* alog  = (const float*)d_in[14];
  const float* Dsw   = (const float*)d_in[15];
  const float* onw   = (const float*)d_in[16];
  const float* onb   = (const float*)d_in[17];
  const float* outw  = (const float*)d_in[18];
  const float* maw   = (const float*)d_in[19];
  const float* mab   = (const float*)d_in[20];
  const float* ahw   = (const float*)d_in[21];
  const float* ahb   = (const float*)d_in[22];
  const float* aww   = (const float*)d_in[23];
  const float* awb   = (const float*)d_in[24];
  const float* pww   = (const float*)d_in[25];
  const float* pwb   = (const float*)d_in[26];
  const float* bnw   = (const float*)d_in[27];
  const float* bnb   = (const float*)d_in[28];
  const float* bnm   = (const float*)d_in[29];
  const float* bnv   = (const float*)d_in[30];

  float* ws = (float*)d_ws;
  float* xd   = ws;                     // 1,179,648
  float* xzA  = xd + 1179648;           // 2,359,296 (dead after k_dwsilu)
  bf16*  hbuf = (bf16*)xzA;             // 6,291,456 bf16 -> 3,145,728 slots (overlay)
  float* xzB  = xzA + 3145728;          // 2,359,296
  float* spare = xzB + 2359296;         // 2,359,296 (unused; was f32 xc)
  float* xdbl = spare + 2359296;        // 5,013,504
  float* ssum = xdbl + 5013504;         // 393,216
  float* ysum = ssum + 393216;          // 2,359,296
  float* xm   = ysum + 2359296;         // 1,179,648
  float* xs2  = xm + 1179648;           // 1,179,648
  bf16*  xch  = (bf16*)xs2;             // overlays xs2 (dead until k_xs)
  float* st   = xs2 + 1179648;          // 512
  float* inm = st, *inr = st + 128, *xmean = st + 256, *xmaxv = st + 384;
  bf16*  wh   = (bf16*)(st + 512);      // 9,216 bf16

  float* outp = (float*)d_out;
  float* down = outp;
  float* skipo = outp + DOWN_SZ;

  dim3 b256(256);
  int nEl = B_ * C_ * L_;

  k_wprep<<<dim3(36), b256, 0, stream>>>(xpw, wh);
  k_dw33<<<dim3((nEl + 255) / 256), b256, 0, stream>>>(x, dw33w, dw33b, xd);
  k_ln_inproj<<<dim3(L_ / 64, BB_), b256, 0, stream>>>(xd, lnw, lnb, inw, xzA, xzB);
  k_dwsilu<<<dim3(BB_ * L_ * DI_ / 256), b256, 0, stream>>>(xzA, cw, cb, xch);
  k_xdbl_mfma<<<dim3(L_ / 64, BB_), b256, 0, stream>>>(xch, wh, xdbl);
  k_scan1<<<dim3(CH_ / 4, K_, BB_), b256, 0, stream>>>(xdbl, xch, dtw, dtb, alog, hbuf, ssum, ysum);
  k_scan2<<<dim3(BB_ * K_ * DI_ * N_ / 256), b256, 0, stream>>>(alog, ssum, hbuf);
  k_scan3<<<dim3(CH_ / 4, K_, BB_), b256, 0, stream>>>(xdbl, xch, dtw, dtb, alog, Dsw, hbuf, ysum);
  k_combine<<<dim3(L_ / 4, BB_), b256, 0, stream>>>(ysum, xzB, xd, onw, onb, outw, mssc, xm);
  k_stats<<<dim3(B_ * C_), dim3(1024), 0, stream>>>(xm, x, inm, inr, xmean, xmaxv);
  k_xs<<<dim3((nEl + 255) / 256), b256, 0, stream>>>(xm, inm, inr, msw, msb, xmean, xmaxv, maw, mab, x, xs2);
  k_axbn<<<dim3((nEl + 255) / 256), b256, 0, stream>>>(xs2, ahw, ahb, aww, awb, bnw, bnb, bnm, bnv, skipo);
  k_pwpool<<<dim3(48, B_, 4), b256, 0, stream>>>(skipo, pww, pwb, down);
}

// Round 6
// 364.944 us; speedup vs baseline: 1.3188x; 1.0226x over previous
//
#include <hip/hip_runtime.h>
#include <hip/hip_bf16.h>

typedef __hip_bfloat16 bf16;
#define DEV __device__ __forceinline__

constexpr int B_ = 2, C_ = 64, H_ = 96, W_ = 96, L_ = 9216;
constexpr int HD_ = 32, DI_ = 64, N_ = 16, K_ = 4, BB_ = 4;
constexpr int OC_ = 128;
constexpr int CH_ = 384, CL_ = 24;          // scan chunking: 384 chunks of 24 steps
constexpr int XST = 36;                     // xdbl row stride: [t0,t1,pad,pad,B*16,C*16]
constexpr float EPSF = 1e-5f;
constexpr int DOWN_SZ = B_ * OC_ * 48 * 48; // 589824

typedef __attribute__((ext_vector_type(8))) short short8;   // 8 bf16 (4 VGPRs)
typedef __attribute__((ext_vector_type(4))) float f32x4;    // MFMA accumulator

DEV float softplusf(float x) { return x > 15.f ? x : __logf(1.f + __expf(x)); }
DEV float b2f(bf16 v) { return __bfloat162float(v); }

// log(1..16): used to detect A[n] = (n+1)*A[0] structure (VMamba default A_logs)
__constant__ float kLogN[16] = {
  0.0f, 0.69314718f, 1.09861229f, 1.38629436f, 1.60943791f, 1.79175947f,
  1.94591015f, 2.07944154f, 2.19722458f, 2.30258509f, 2.39789527f,
  2.48490665f, 2.56494936f, 2.63905733f, 2.70805020f, 2.77258872f};

// per-chunk scan addressing: spatial idx = idx0 + s*stride, s in [0,CL)
DEV void chunk_addr(int k, int chunk, int& idx0, int& stride) {
  int r4 = chunk & 3, q = chunk >> 2;
  if (k == 0)      { idx0 = chunk * CL_;                        stride = 1;   }
  else if (k == 1) { idx0 = (24 * r4) * 96 + q;                 stride = 96;  }
  else if (k == 2) { idx0 = L_ - 1 - chunk * CL_;               stride = -1;  }
  else             { idx0 = (95 - 24 * r4) * 96 + (95 - q);     stride = -96; }
}

// 16 decay powers e1^(n+1) via log-depth binary tree (depth 4, 14 muls)
DEV void pow_tree(float e1, float* ep) {
  float e2 = e1 * e1, e4 = e2 * e2, e8 = e4 * e4;
  float e3 = e2 * e1, e5 = e4 * e1, e6 = e4 * e2, e7 = e4 * e3;
  ep[0] = e1;  ep[1] = e2;  ep[2] = e3;  ep[3] = e4;
  ep[4] = e5;  ep[5] = e6;  ep[6] = e7;  ep[7] = e8;
  ep[8] = e8 * e1;  ep[9] = e8 * e2;  ep[10] = e8 * e3;  ep[11] = e8 * e4;
  ep[12] = e8 * e5; ep[13] = e8 * e6; ep[14] = e8 * e7;  ep[15] = e8 * e8;
}

// ---------------- A: depthwise 3x3 (x -> xd, f32) ----------------
__global__ void k_dw33(const float* __restrict__ x, const float* __restrict__ w,
                       const float* __restrict__ bias, float* __restrict__ out) {
  int t = blockIdx.x * 256 + threadIdx.x;
  if (t >= B_ * C_ * L_) return;
  int wi = t % W_, hi = (t / W_) % H_, c = (t / L_) % C_;
  float acc = bias[c];
#pragma unroll
  for (int dy = -1; dy <= 1; dy++) {
    int hh = hi + dy; if (hh < 0 || hh >= H_) continue;
#pragma unroll
    for (int dx = -1; dx <= 1; dx++) {
      int ww = wi + dx; if (ww < 0 || ww >= W_) continue;
      acc = fmaf(x[t + dy * W_ + dx], w[c * 9 + (dy + 1) * 3 + (dx + 1)], acc);
    }
  }
  out[t] = acc;
}

// ---------------- B: LayerNorm(32) + in_proj (32->128), 64-idx tile GEMM ----------------
__global__ __launch_bounds__(256, 4) void k_ln_inproj(
    const float* __restrict__ xd, const float* __restrict__ lnw,
    const float* __restrict__ lnb, const float* __restrict__ inw,
    float* __restrict__ xzA, float* __restrict__ xzB) {
  int bb = blockIdx.y, t = threadIdx.x;
  int b = bb & 1, co = (bb >> 1) * HD_;
  int idx0 = blockIdx.x * 64;
  __shared__ float xds[32 * 68];
  __shared__ float meanA[64], rstdA[64];
  int lane = t & 63;
  for (int r = 0; r < 8; r++) {
    int c = r * 4 + (t >> 6);
    xds[c * 68 + lane] = xd[(size_t)(b * C_ + co + c) * L_ + idx0 + lane];
  }
  __syncthreads();
  if (t < 64) {
    float s = 0.f, sq = 0.f;
#pragma unroll
    for (int c = 0; c < 32; c++) { float v = xds[c * 68 + t]; s += v; sq = fmaf(v, v, sq); }
    float mean = s * (1.f / HD_);
    float var = sq * (1.f / HD_) - mean * mean;
    meanA[t] = mean; rstdA[t] = rsqrtf(var + EPSF);
  }
  __syncthreads();
  for (int i = t; i < 2048; i += 256) {
    int c = i >> 6, idx = i & 63;
    float v = xds[c * 68 + idx];
    xds[c * 68 + idx] = (v - meanA[idx]) * rstdA[idx] * lnw[c] + lnb[c];
  }
  __syncthreads();
  int oc = t & 127, g = t >> 7;
  float acc[32];
#pragma unroll
  for (int j = 0; j < 32; j++) acc[j] = 0.f;
  for (int c = 0; c < 32; c++) {
    float wv = inw[c * 128 + oc];
    const float4* row = reinterpret_cast<const float4*>(&xds[c * 68 + g * 32]);
#pragma unroll
    for (int j4 = 0; j4 < 8; j4++) {
      float4 xv = row[j4];
      acc[j4 * 4 + 0] = fmaf(xv.x, wv, acc[j4 * 4 + 0]);
      acc[j4 * 4 + 1] = fmaf(xv.y, wv, acc[j4 * 4 + 1]);
      acc[j4 * 4 + 2] = fmaf(xv.z, wv, acc[j4 * 4 + 2]);
      acc[j4 * 4 + 3] = fmaf(xv.w, wv, acc[j4 * 4 + 3]);
    }
  }
  float* dst = (oc < 64) ? xzA : xzB;
  int occ = oc & 63;
#pragma unroll
  for (int j = 0; j < 32; j++) {
    int idx = g * 32 + j;
    dst[(size_t)(bb * L_ + idx0 + idx) * 64 + occ] = acc[j];
  }
}

// ---------------- C: depthwise 3x3 + SiLU -> xch (bf16, [bb,l,d]) ----------------
__global__ void k_dwsilu(const float* __restrict__ xzA, const float* __restrict__ cw,
                         const float* __restrict__ cb, bf16* __restrict__ xch) {
  int t = blockIdx.x * 256 + threadIdx.x;
  int d = t & 63, idx = (t >> 6) % L_, bb = t / (L_ * DI_);
  int wi = idx % W_, hi = idx / W_;
  float acc = cb[d];
#pragma unroll
  for (int dy = -1; dy <= 1; dy++) {
    int hh = hi + dy; if (hh < 0 || hh >= H_) continue;
#pragma unroll
    for (int dx = -1; dx <= 1; dx++) {
      int ww = wi + dx; if (ww < 0 || ww >= W_) continue;
      acc = fmaf(xzA[(size_t)(bb * L_ + hh * W_ + ww) * 64 + d],
                 cw[d * 9 + (dy + 1) * 3 + (dx + 1)], acc);
    }
  }
  acc = acc / (1.f + __expf(-acc));
  xch[t] = __float2bfloat16(acc);
}

// ---------------- D0: weight prep — 136x64 f32 -> 144x64 bf16 (zero-padded) ----------------
__global__ void k_wprep(const float* __restrict__ xpw, bf16* __restrict__ wh) {
  int i = blockIdx.x * 256 + threadIdx.x;  // 144*64
  if (i >= 144 * 64) return;
  int n = i >> 6;
  wh[i] = __float2bfloat16(n < 136 ? xpw[i] : 0.f);
}

// ---------------- D: x_dbl projection via MFMA: [36864 x 64] @ [64 x 136] ----------------
// output layout: row stride XST=36: [dt0, dt1, pad, pad, B0..B15, C0..C15]
__global__ __launch_bounds__(256, 4) void k_xdbl_mfma(
    const bf16* __restrict__ xch, const bf16* __restrict__ wh,
    float* __restrict__ xdbl) {
  int w = threadIdx.x >> 6, lane = threadIdx.x & 63;
  int bb = blockIdx.y;
  int mtile = blockIdx.x * 4 + w;
  int idx0 = mtile * 16;
  int m = lane & 15, quad = lane >> 4;
  const bf16* arow = xch + ((size_t)bb * L_ + idx0 + m) * 64 + quad * 8;
  short8 a0 = *reinterpret_cast<const short8*>(arow);
  short8 a1 = *reinterpret_cast<const short8*>(arow + 32);
#pragma unroll
  for (int nt = 0; nt < 9; nt++) {
    int n = nt * 16 + m;
    const bf16* brow = wh + n * 64 + quad * 8;
    short8 b0 = *reinterpret_cast<const short8*>(brow);
    short8 b1 = *reinterpret_cast<const short8*>(brow + 32);
    f32x4 acc = {0.f, 0.f, 0.f, 0.f};
    acc = __builtin_amdgcn_mfma_f32_16x16x32_bf16(a0, b0, acc, 0, 0, 0);
    acc = __builtin_amdgcn_mfma_f32_16x16x32_bf16(a1, b1, acc, 0, 0, 0);
    if (n < 136) {
      int k4 = (n >= 102) ? 3 : (n >= 68) ? 2 : (n >= 34) ? 1 : 0;
      int c = n - k4 * 34;
      int col = (c < 2) ? c : c + 2;    // dt at 0..1, B at 4..19, C at 20..35
      float* dst = xdbl + ((size_t)(bb * K_ + k4) * L_ + idx0 + quad * 4) * XST + col;
      dst[0] = acc[0]; dst[XST] = acc[1]; dst[2 * XST] = acc[2]; dst[3 * XST] = acc[3];
    }
  }
}

// ---------------- E: scan phase 1 — per-chunk local state (h0=0) + sum(dt) ----------------
__global__ __launch_bounds__(256, 4) void k_scan1(
    const float* __restrict__ xdbl, const bf16* __restrict__ xch,
    const float* __restrict__ dtw, const float* __restrict__ dtb,
    const float* __restrict__ alog, bf16* __restrict__ hbuf,
    float* __restrict__ ssum, float* __restrict__ ysum) {
  int w = threadIdx.x >> 6, d = threadIdx.x & 63;
  int chunk = blockIdx.x * 4 + w, k = blockIdx.y, bb = blockIdx.z;
  if (k == 0) {  // zero ysum slice before scan3's atomics
    float* yb = ysum + ((size_t)bb * L_ + chunk * CL_) * DI_ + d;
#pragma unroll
    for (int j = 0; j < CL_; j++) yb[j * DI_] = 0.f;
  }
  float w0 = dtw[(k * DI_ + d) * 2 + 0], w1 = dtw[(k * DI_ + d) * 2 + 1];
  float bia = dtb[k * DI_ + d];
  const float* al = alog + (k * DI_ + d) * N_;
  float a0 = al[0];
  bool lin = true;
#pragma unroll
  for (int n = 1; n < N_; n++) lin = lin && (fabsf(al[n] - a0 - kLogN[n]) < 3e-5f);
  bool chain = (__ballot(lin) == ~0ull);
  float A1 = -__expf(a0);
  float h[N_];
#pragma unroll
  for (int n = 0; n < N_; n++) h[n] = 0.f;
  int idx0, stride;
  chunk_addr(k, chunk, idx0, stride);
  const float* xdb = xdbl + (size_t)(bb * K_ + k) * L_ * XST;
  const bf16* xcb = xch + (size_t)bb * L_ * DI_;
  float S = 0.f;
  int idx = idx0;
  const float* pr = xdb + (size_t)idx * XST;
  float t0 = pr[0], t1 = pr[1];
  float u = b2f(xcb[(size_t)idx * DI_ + d]);
  float Bc[16];
  *(float4*)&Bc[0]  = *(const float4*)(pr + 4);
  *(float4*)&Bc[4]  = *(const float4*)(pr + 8);
  *(float4*)&Bc[8]  = *(const float4*)(pr + 12);
  *(float4*)&Bc[12] = *(const float4*)(pr + 16);
  if (chain) {
    for (int s = 0; s < CL_; s++) {
      int nidx = (s + 1 < CL_) ? idx + stride : idx0;
      const float* np = xdb + (size_t)nidx * XST;
      float nt0 = np[0], nt1 = np[1];
      float nu = b2f(xcb[(size_t)nidx * DI_ + d]);
      float Bn[16];
      *(float4*)&Bn[0]  = *(const float4*)(np + 4);
      *(float4*)&Bn[4]  = *(const float4*)(np + 8);
      *(float4*)&Bn[8]  = *(const float4*)(np + 12);
      *(float4*)&Bn[12] = *(const float4*)(np + 16);
      float dt = softplusf(fmaf(t0, w0, fmaf(t1, w1, bia)));
      S += dt;
      float du = dt * u;
      float ep[16];
      pow_tree(__expf(dt * A1), ep);
#pragma unroll
      for (int n = 0; n < N_; n++) h[n] = fmaf(ep[n], h[n], du * Bc[n]);
      idx = nidx; t0 = nt0; t1 = nt1; u = nu;
#pragma unroll
      for (int n = 0; n < N_; n++) Bc[n] = Bn[n];
    }
  } else {
    float A[N_];
#pragma unroll
    for (int n = 0; n < N_; n++) A[n] = -__expf(al[n]);
    for (int s = 0; s < CL_; s++) {
      int nidx = (s + 1 < CL_) ? idx + stride : idx0;
      const float* np = xdb + (size_t)nidx * XST;
      float nt0 = np[0], nt1 = np[1];
      float nu = b2f(xcb[(size_t)nidx * DI_ + d]);
      float Bn[16];
      *(float4*)&Bn[0]  = *(const float4*)(np + 4);
      *(float4*)&Bn[4]  = *(const float4*)(np + 8);
      *(float4*)&Bn[8]  = *(const float4*)(np + 12);
      *(float4*)&Bn[12] = *(const float4*)(np + 16);
      float dt = softplusf(fmaf(t0, w0, fmaf(t1, w1, bia)));
      S += dt;
      float du = dt * u;
#pragma unroll
      for (int n = 0; n < N_; n++)
        h[n] = fmaf(__expf(dt * A[n]), h[n], du * Bc[n]);
      idx = nidx; t0 = nt0; t1 = nt1; u = nu;
#pragma unroll
      for (int n = 0; n < N_; n++) Bc[n] = Bn[n];
    }
  }
  size_t base = (size_t)((bb * K_ + k) * CH_ + chunk) * DI_ + d;
  ssum[base] = S;
#pragma unroll
  for (int n = 0; n < N_; n++) hbuf[base * N_ + n] = __float2bfloat16(h[n]);
}

// ---------------- F: scan phase 2 — exclusive scan over chunk summaries (pipelined) ----------------
__global__ void k_scan2(const float* __restrict__ alog, const float* __restrict__ ssum,
                        bf16* __restrict__ hbuf) {
  int t = blockIdx.x * 256 + threadIdx.x;
  int n = t & 15, d = (t >> 4) & 63, kk = (t >> 10) & 3, bb = t >> 12;
  float A = -__expf(alog[(kk * DI_ + d) * N_ + n]);
  size_t row = (size_t)(bb * K_ + kk) * CH_ * DI_ + d;
  constexpr int U = 16;
  float Sb[U], hb[U];
#pragma unroll
  for (int j = 0; j < U; j++) {
    size_t sb = row + (size_t)j * DI_;
    Sb[j] = ssum[sb]; hb[j] = b2f(hbuf[sb * N_ + n]);
  }
  float hp = 0.f;
  for (int c = 0; c < CH_; c += U) {
    float S2[U], h2[U];
    if (c + U < CH_) {
#pragma unroll
      for (int j = 0; j < U; j++) {
        size_t sb = row + (size_t)(c + U + j) * DI_;
        S2[j] = ssum[sb]; h2[j] = b2f(hbuf[sb * N_ + n]);
      }
    } else {
#pragma unroll
      for (int j = 0; j < U; j++) { S2[j] = 0.f; h2[j] = 0.f; }
    }
#pragma unroll
    for (int j = 0; j < U; j++) {
      size_t sb = row + (size_t)(c + j) * DI_;
      float e = __expf(A * Sb[j]);
      hbuf[sb * N_ + n] = __float2bfloat16(hp);
      hp = fmaf(e, hp, hb[j]);
    }
#pragma unroll
    for (int j = 0; j < U; j++) { Sb[j] = S2[j]; hb[j] = h2[j]; }
  }
}

// ---------------- G: scan phase 3 — replay with true init, emit y into ysum ----------------
__global__ __launch_bounds__(256, 4) void k_scan3(
    const float* __restrict__ xdbl, const bf16* __restrict__ xch,
    const float* __restrict__ dtw, const float* __restrict__ dtb,
    const float* __restrict__ alog, const float* __restrict__ Dsw,
    const bf16* __restrict__ hbuf, float* __restrict__ ysum) {
  int w = threadIdx.x >> 6, d = threadIdx.x & 63;
  int chunk = blockIdx.x * 4 + w, k = blockIdx.y, bb = blockIdx.z;
  float w0 = dtw[(k * DI_ + d) * 2 + 0], w1 = dtw[(k * DI_ + d) * 2 + 1];
  float bia = dtb[k * DI_ + d];
  float Dk = Dsw[k * DI_ + d];
  const float* al = alog + (k * DI_ + d) * N_;
  float a0 = al[0];
  bool lin = true;
#pragma unroll
  for (int n = 1; n < N_; n++) lin = lin && (fabsf(al[n] - a0 - kLogN[n]) < 3e-5f);
  bool chain = (__ballot(lin) == ~0ull);
  float A1 = -__expf(a0);
  float h[N_];
  size_t base = (size_t)((bb * K_ + k) * CH_ + chunk) * DI_ + d;
#pragma unroll
  for (int n = 0; n < N_; n++) h[n] = b2f(hbuf[base * N_ + n]);
  int idx0, stride;
  chunk_addr(k, chunk, idx0, stride);
  const float* xdb = xdbl + (size_t)(bb * K_ + k) * L_ * XST;
  const bf16* xcb = xch + (size_t)bb * L_ * DI_;
  float* yb = ysum + (size_t)bb * L_ * DI_;
  int idx = idx0;
  const float* pr = xdb + (size_t)idx * XST;
  float t0 = pr[0], t1 = pr[1];
  float u = b2f(xcb[(size_t)idx * DI_ + d]);
  float Bc[16], Cc[16];
  *(float4*)&Bc[0]  = *(const float4*)(pr + 4);
  *(float4*)&Bc[4]  = *(const float4*)(pr + 8);
  *(float4*)&Bc[8]  = *(const float4*)(pr + 12);
  *(float4*)&Bc[12] = *(const float4*)(pr + 16);
  *(float4*)&Cc[0]  = *(const float4*)(pr + 20);
  *(float4*)&Cc[4]  = *(const float4*)(pr + 24);
  *(float4*)&Cc[8]  = *(const float4*)(pr + 28);
  *(float4*)&Cc[12] = *(const float4*)(pr + 32);
  if (chain) {
    for (int s = 0; s < CL_; s++) {
      int nidx = (s + 1 < CL_) ? idx + stride : idx0;
      const float* np = xdb + (size_t)nidx * XST;
      float nt0 = np[0], nt1 = np[1];
      float nu = b2f(xcb[(size_t)nidx * DI_ + d]);
      float Bn[16], Cn[16];
      *(float4*)&Bn[0]  = *(const float4*)(np + 4);
      *(float4*)&Bn[4]  = *(const float4*)(np + 8);
      *(float4*)&Bn[8]  = *(const float4*)(np + 12);
      *(float4*)&Bn[12] = *(const float4*)(np + 16);
      *(float4*)&Cn[0]  = *(const float4*)(np + 20);
      *(float4*)&Cn[4]  = *(const float4*)(np + 24);
      *(float4*)&Cn[8]  = *(const float4*)(np + 28);
      *(float4*)&Cn[12] = *(const float4*)(np + 32);
      float dt = softplusf(fmaf(t0, w0, fmaf(t1, w1, bia)));
      float du = dt * u;
      float ep[16];
      pow_tree(__expf(dt * A1), ep);
      float y = 0.f;
#pragma unroll
      for (int n = 0; n < N_; n++) {
        h[n] = fmaf(ep[n], h[n], du * Bc[n]);
        y = fmaf(h[n], Cc[n], y);
      }
      y = fmaf(Dk, u, y);
      atomicAdd(&yb[(size_t)idx * DI_ + d], y);
      idx = nidx; t0 = nt0; t1 = nt1; u = nu;
#pragma unroll
      for (int n = 0; n < N_; n++) { Bc[n] = Bn[n]; Cc[n] = Cn[n]; }
    }
  } else {
    float A[N_];
#pragma unroll
    for (int n = 0; n < N_; n++) A[n] = -__expf(al[n]);
    for (int s = 0; s < CL_; s++) {
      int nidx = (s + 1 < CL_) ? idx + stride : idx0;
      const float* np = xdb + (size_t)nidx * XST;
      float nt0 = np[0], nt1 = np[1];
      float nu = b2f(xcb[(size_t)nidx * DI_ + d]);
      float Bn[16], Cn[16];
      *(float4*)&Bn[0]  = *(const float4*)(np + 4);
      *(float4*)&Bn[4]  = *(const float4*)(np + 8);
      *(float4*)&Bn[8]  = *(const float4*)(np + 12);
      *(float4*)&Bn[12] = *(const float4*)(np + 16);
      *(float4*)&Cn[0]  = *(const float4*)(np + 20);
      *(float4*)&Cn[4]  = *(const float4*)(np + 24);
      *(float4*)&Cn[8]  = *(const float4*)(np + 28);
      *(float4*)&Cn[12] = *(const float4*)(np + 32);
      float dt = softplusf(fmaf(t0, w0, fmaf(t1, w1, bia)));
      float du = dt * u;
      float y = 0.f;
#pragma unroll
      for (int n = 0; n < N_; n++) {
        h[n] = fmaf(__expf(dt * A[n]), h[n], du * Bc[n]);
        y = fmaf(h[n], Cc[n], y);
      }
      y = fmaf(Dk, u, y);
      atomicAdd(&yb[(size_t)idx * DI_ + d], y);
      idx = nidx; t0 = nt0; t1 = nt1; u = nu;
#pragma unroll
      for (int n = 0; n < N_; n++) { Bc[n] = Bn[n]; Cc[n] = Cn[n]; }
    }
  }
}

// ---------------- H: LN(64)*silu(z), out_proj (64->32), residual -> xm ----------------
__global__ void k_combine(const float* __restrict__ ysum, const float* __restrict__ xzB,
                          const float* __restrict__ xd, const float* __restrict__ onw,
                          const float* __restrict__ onb, const float* __restrict__ outw,
                          const float* __restrict__ mssc, float* __restrict__ xm) {
  int w = threadIdx.x >> 6, d = threadIdx.x & 63;
  int idx = blockIdx.x * 4 + w, bb = blockIdx.y;
  int b = bb & 1, co = (bb >> 1) * HD_;
  float y = ysum[(size_t)(bb * L_ + idx) * DI_ + d];
  float s = y, sq = y * y;
#pragma unroll
  for (int m = 1; m < 64; m <<= 1) { s += __shfl_xor(s, m, 64); sq += __shfl_xor(sq, m, 64); }
  float mean = s * (1.f / DI_);
  float var = sq * (1.f / DI_) - mean * mean;
  float rstd = rsqrtf(var + EPSF);
  float yn = (y - mean) * rstd * onw[d] + onb[d];
  float z = xzB[(size_t)(bb * L_ + idx) * 64 + d];
  float g = yn * (z / (1.f + __expf(-z)));
  __shared__ float gs[4][DI_];
  gs[w][d] = g;
  __syncthreads();
  if (d < HD_) {
    float acc = 0.f;
#pragma unroll
    for (int dd = 0; dd < DI_; dd++) acc = fmaf(gs[w][dd], outw[dd * HD_ + d], acc);
    size_t xi = (size_t)(b * C_ + co + d) * L_ + idx;
    float xp = xd[xi];
    xm[xi] = mssc[0] * xp + xp + acc;
  }
}

// ---------------- I: fused instance-norm stats (xm) + global mean/max pool (x) ----------------
__global__ __launch_bounds__(1024) void k_stats(
    const float* __restrict__ xm, const float* __restrict__ x,
    float* __restrict__ inm, float* __restrict__ inr,
    float* __restrict__ xmean, float* __restrict__ xmax) {
  int bc = blockIdx.x, t = threadIdx.x;
  const float* pm = xm + (size_t)bc * L_;
  const float* px = x + (size_t)bc * L_;
  float s = 0.f, sq = 0.f, xs = 0.f, mx = -1e30f;
  for (int i = t; i < L_; i += 1024) {
    float v = pm[i]; s += v; sq = fmaf(v, v, sq);
    float xv = px[i]; xs += xv; mx = fmaxf(mx, xv);
  }
  __shared__ float red[64];
#pragma unroll
  for (int m = 1; m < 64; m <<= 1) {
    s += __shfl_xor(s, m, 64); sq += __shfl_xor(sq, m, 64);
    xs += __shfl_xor(xs, m, 64); mx = fmaxf(mx, __shfl_xor(mx, m, 64));
  }
  int wid = t >> 6;
  if ((t & 63) == 0) { red[wid] = s; red[16 + wid] = sq; red[32 + wid] = xs; red[48 + wid] = mx; }
  __syncthreads();
  if (t == 0) {
    s = 0.f; sq = 0.f; xs = 0.f; mx = -1e30f;
#pragma unroll
    for (int i = 0; i < 16; i++) {
      s += red[i]; sq += red[16 + i]; xs += red[32 + i]; mx = fmaxf(mx, red[48 + i]);
    }
    float mean = s * (1.f / L_);
    float var = sq * (1.f / L_) - mean * mean;
    inm[bc] = mean;
    inr[bc] = rsqrtf(var + EPSF);
    xmean[bc] = xs * (1.f / L_);
    xmax[bc] = mx;
  }
}

// ---------------- L: IN apply + leaky_relu + sigmoid-gate*x -> xs2 ----------------
__global__ void k_xs(const float* __restrict__ xm, const float* __restrict__ inm,
                     const float* __restrict__ inr, const float* __restrict__ msw,
                     const float* __restrict__ msb, const float* __restrict__ xmean,
                     const float* __restrict__ xmax, const float* __restrict__ maw,
                     const float* __restrict__ mab, const float* __restrict__ x,
                     float* __restrict__ xs2) {
  int t = blockIdx.x * 256 + threadIdx.x;
  int bc = t / L_, c = bc & 63, b = bc >> 6;   // uniform per block (256 | L)
  __shared__ float gsh;
  if (threadIdx.x < 64) {
    int ic = threadIdx.x;
    float p = xmean[b * 64 + ic] * maw[(c * 128 + ic) * 9 + 4]
            + xmax[b * 64 + ic] * maw[(c * 128 + 64 + ic) * 9 + 4];
#pragma unroll
    for (int m = 1; m < 64; m <<= 1) p += __shfl_xor(p, m, 64);
    if (ic == 0) gsh = 1.f / (1.f + __expf(-(p + mab[c])));
  }
  __syncthreads();
  float gate = gsh;
  float v = xm[t];
  v = (v - inm[bc]) * inr[bc] * msw[c] + msb[c];
  v = v > 0.f ? v : 0.01f * v;
  xs2[t] = v + gate * x[t];
}

// ---------------- M: axial dw convs + BN + relu -> skip (straight to d_out) ----------------
__global__ void k_axbn(const float* __restrict__ xs2, const float* __restrict__ hw,
                       const float* __restrict__ hb, const float* __restrict__ wwt,
                       const float* __restrict__ wb, const float* __restrict__ bnw,
                       const float* __restrict__ bnb, const float* __restrict__ bnm,
                       const float* __restrict__ bnv, float* __restrict__ skipo) {
  int t = blockIdx.x * 256 + threadIdx.x;
  if (t >= B_ * C_ * L_) return;
  int wi = t % W_, hi = (t / W_) % H_, c = (t / L_) % C_;
  float a = xs2[t];
  float hacc = hb[c];
#pragma unroll
  for (int dy = -1; dy <= 1; dy++) {
    int hh = hi + dy; if (hh < 0 || hh >= H_) continue;
    hacc = fmaf(xs2[t + dy * W_], hw[c * 3 + dy + 1], hacc);
  }
  float wacc = wb[c];
#pragma unroll
  for (int dx = -1; dx <= 1; dx++) {
    int ww = wi + dx; if (ww < 0 || ww >= W_) continue;
    wacc = fmaf(xs2[t + dx], wwt[c * 3 + dx + 1], wacc);
  }
  float v = a + hacc + wacc;
  float sv = (v - bnm[c]) * rsqrtf(bnv[c] + EPSF) * bnw[c] + bnb[c];
  skipo[t] = fmaxf(sv, 0.f);
}

// ---------------- N: 1x1 conv (64->128) + 2x2 maxpool -> down (oc split over z) ----------------
__global__ void k_pwpool(const float* __restrict__ skipo, const float* __restrict__ pww,
                         const float* __restrict__ pwb, float* __restrict__ down) {
  int h2 = blockIdx.x, b = blockIdx.y, t = threadIdx.x;
  int oc0 = blockIdx.z * 32;
  __shared__ float sk[64 * 192];  // [c][r(2)][w(96)]
  for (int i = t; i < 64 * 192; i += 256) {
    int c = i / 192, rw = i % 192, r = rw / 96, wcol = rw % 96;
    sk[i] = skipo[((size_t)(b * C_ + c) * H_ + (2 * h2 + r)) * W_ + wcol];
  }
  __syncthreads();
  for (int o = t; o < 32 * 48; o += 256) {
    int oc = oc0 + o / 48, w2 = o % 48;
    float s0 = 0.f, s1 = 0.f, s2 = 0.f, s3 = 0.f;
#pragma unroll 8
    for (int c = 0; c < 64; c++) {
      float wv = pww[oc * 64 + c];
      const float* sp = &sk[c * 192 + 2 * w2];
      s0 = fmaf(sp[0], wv, s0);
      s1 = fmaf(sp[1], wv, s1);
      s2 = fmaf(sp[96], wv, s2);
      s3 = fmaf(sp[97], wv, s3);
    }
    float v = fmaxf(fmaxf(s0, s1), fmaxf(s2, s3)) + pwb[oc];
    down[((size_t)(b * OC_ + oc) * 48 + h2) * 48 + w2] = v;
  }
}

extern "C" void kernel_launch(void* const* d_in, const int* in_sizes, int n_in,
                              void* d_out, int out_size, void* d_ws, size_t ws_size,
                              hipStream_t stream) {
  const float* x     = (const float*)d_in[0];
  const float* dw33w = (const float*)d_in[1];
  const float* dw33b = (const float*)d_in[2];
  const float* msw   = (const float*)d_in[3];
  const float* msb   = (const float*)d_in[4];
  const float* mssc  = (const float*)d_in[5];
  const float* lnw   = (const float*)d_in[6];
  const float* lnb   = (const float*)d_in[7];
  const float* inw   = (const float*)d_in[8];
  const float* cw    = (const float*)d_in[9];
  const float* cb    = (const float*)d_in[10];
  const float* xpw   = (const float*)d_in[11];
  const float* dtw   = (const float*)d_in[12];
  const float* dtb   = (const float*)d_in[13];
  const float* alog  = (const float*)d_in[14];
  const float* Dsw   = (const float*)d_in[15];
  const float* onw   = (const float*)d_in[16];
  const float* onb   = (const float*)d_in[17];
  const float* outw  = (const float*)d_in[18];
  const float* maw   = (const float*)d_in[19];
  const float* mab   = (const float*)d_in[20];
  const float* ahw   = (const float*)d_in[21];
  const float* ahb   = (const float*)d_in[22];
  const float* aww   = (const float*)d_in[23];
  const float* awb   = (const float*)d_in[24];
  const float* pww   = (const float*)d_in[25];
  const float* pwb   = (const float*)d_in[26];
  const float* bnw   = (const float*)d_in[27];
  const float* bnb   = (const float*)d_in[28];
  const float* bnm   = (const float*)d_in[29];
  const float* bnv   = (const float*)d_in[30];

  float* ws = (float*)d_ws;
  float* xd   = ws;                     // 1,179,648
  float* xzA  = xd + 1179648;           // block of 3,145,728 (xp half; hbuf overlays)
  bf16*  hbuf = (bf16*)xzA;             // 6,291,456 bf16 -> 3,145,728 float slots
  float* xzB  = xzA + 3145728;          // 2,359,296
  float* xdbl = xzB + 2359296;          // BB*K*L*36 = 5,308,416
  float* ssum = xdbl + 5308416;         // 393,216
  float* ysum = ssum + 393216;          // 2,359,296
  float* xm   = ysum + 2359296;         // 1,179,648
  float* xs2  = xm + 1179648;           // 1,179,648
  bf16*  xch  = (bf16*)xs2;             // overlays xs2 (dead until k_xs)
  float* st   = xs2 + 1179648;          // 512
  float* inm = st, *inr = st + 128, *xmean = st + 256, *xmaxv = st + 384;
  bf16*  wh   = (bf16*)(st + 512);      // 9,216 bf16

  float* outp = (float*)d_out;
  float* down = outp;
  float* skipo = outp + DOWN_SZ;

  dim3 b256(256);
  int nEl = B_ * C_ * L_;

  k_wprep<<<dim3(36), b256, 0, stream>>>(xpw, wh);
  k_dw33<<<dim3((nEl + 255) / 256), b256, 0, stream>>>(x, dw33w, dw33b, xd);
  k_ln_inproj<<<dim3(L_ / 64, BB_), b256, 0, stream>>>(xd, lnw, lnb, inw, xzA, xzB);
  k_dwsilu<<<dim3(BB_ * L_ * DI_ / 256), b256, 0, stream>>>(xzA, cw, cb, xch);
  k_xdbl_mfma<<<dim3(L_ / 64, BB_), b256, 0, stream>>>(xch, wh, xdbl);
  k_scan1<<<dim3(CH_ / 4, K_, BB_), b256, 0, stream>>>(xdbl, xch, dtw, dtb, alog, hbuf, ssum, ysum);
  k_scan2<<<dim3(BB_ * K_ * DI_ * N_ / 256), b256, 0, stream>>>(alog, ssum, hbuf);
  k_scan3<<<dim3(CH_ / 4, K_, BB_), b256, 0, stream>>>(xdbl, xch, dtw, dtb, alog, Dsw, hbuf, ysum);
  k_combine<<<dim3(L_ / 4, BB_), b256, 0, stream>>>(ysum, xzB, xd, onw, onb, outw, mssc, xm);
  k_stats<<<dim3(B_ * C_), dim3(1024), 0, stream>>>(xm, x, inm, inr, xmean, xmaxv);
  k_xs<<<dim3((nEl + 255) / 256), b256, 0, stream>>>(xm, inm, inr, msw, msb, xmean, xmaxv, maw, mab, x, xs2);
  k_axbn<<<dim3((nEl + 255) / 256), b256, 0, stream>>>(xs2, ahw, ahb, aww, awb, bnw, bnb, bnm, bnv, skipo);
  k_pwpool<<<dim3(48, B_, 4), b256, 0, stream>>>(skipo, pww, pwb, down);
}